// Round 11
// baseline (145.354 us; speedup 1.0000x reference)
//
#include <hip/hip_runtime.h>
#include <stdint.h>

#define BATCH 8
#define LTOK 1024
#define DMODEL 512
#define NHEAD 8
#define DHEAD 64

typedef unsigned short u16;
typedef u16 u16x8 __attribute__((ext_vector_type(8)));
typedef short bf16x8 __attribute__((ext_vector_type(8)));
typedef float f32x4 __attribute__((ext_vector_type(4)));

#define MFMA16(a,b,c) __builtin_amdgcn_mfma_f32_16x16x32_bf16((a),(b),(c),0,0,0)

__device__ __forceinline__ float bf2f(u16 x){
  union{unsigned u; float f;} v; v.u = ((unsigned)x)<<16; return v.f;
}
__device__ __forceinline__ u16 f2bf(float f){
  union{float f; unsigned u;} v; v.f = f;
  unsigned r = v.u + 0x7fffu + ((v.u>>16)&1u);
  return (u16)(r>>16);
}

__device__ __forceinline__ void gload_lds16(const u16* g, u16* l){
  __builtin_amdgcn_global_load_lds(
      (const __attribute__((address_space(1))) void*)g,
      (__attribute__((address_space(3))) void*)l,
      16, 0, 0);
}

// ---------------- fp32 -> bf16 elementwise convert ------------------------------
__global__ __launch_bounds__(256) void convert_k(const float* __restrict__ src,
                                                 u16* __restrict__ dst, int n){
  const int i = (blockIdx.x*256 + threadIdx.x)*8;
  if (i >= n) return;
  u16x8 v;
  #pragma unroll
  for (int j=0;j<8;j++) v[j] = f2bf(src[i+j]);
  *(u16x8*)(dst + i) = v;
}

// ---------------- 64x64 tiled transpose fp32->bf16: dst[c][r] = src[r][c] -------
__global__ __launch_bounds__(256) void transpose_f2b(const float* __restrict__ src,
                                                     u16* __restrict__ dst,
                                                     int R, int C){
  __shared__ __align__(16) u16 t[64][72];
  const int b  = blockIdx.z;
  const int r0 = blockIdx.x*64, c0 = blockIdx.y*64;
  const float* s = src + (size_t)b*R*C;
  u16* d         = dst + (size_t)b*R*C;
  const int tid = threadIdx.x;
  const int row = tid>>3, ch = (tid&7)*8;
  #pragma unroll
  for (int rr=0; rr<64; rr+=32){
    const float* p = s + (size_t)(r0+row+rr)*C + c0 + ch;
    u16x8 v;
    #pragma unroll
    for (int j=0;j<8;j++) v[j] = f2bf(p[j]);
    *(u16x8*)&t[row+rr][ch] = v;
  }
  __syncthreads();
  #pragma unroll
  for (int rr=0; rr<64; rr+=32){
    const int dr = row+rr;
    u16x8 v;
    #pragma unroll
    for (int j=0;j<8;j++) v[j] = t[ch+j][dr];
    *(u16x8*)(d + (size_t)(c0+dr)*R + r0 + ch) = v;
  }
}

// stage a 64x64 bf16 tile into linear LDS with the read-swizzle pre-applied to
// the source k-chunk (rule 21: filler granule (r, cc^(r&7)) holds A[r][cc*8])
__device__ __forceinline__ void stage_gemm(const u16* __restrict__ src,
                                           int row0, int k0, u16* lds, int tid){
  #pragma unroll
  for (int s2=0; s2<2; ++s2){
    const int slot = tid + s2*256;
    const int row = slot>>3, ch8 = slot&7;
    const int k = k0 + ((ch8 ^ (row&7))<<3);
    gload_lds16(src + (size_t)(row0+row)*DMODEL + k, lds + slot*8);
  }
}

// ---------------- QKV projection -> MFMA-fragment-major K/Q and V^T tiles -------
// Kf[bh][t][frag=ks*4+nj][lane=lg*16+lr][j]  holds K[t*64+nj*16+lr][ks*32+lg*8+j]
// Vf[bh][t][frag=ks*4+dj][lane=lg*16+lr][j]  holds V[t*64+ks*32+lg*8+j][dj*16+lr]
__global__ __launch_bounds__(256) void qkv_gemm(const u16* __restrict__ A,
                                                const u16* __restrict__ W,
                                                u16* __restrict__ Kf,
                                                u16* __restrict__ Vf){
  __shared__ __align__(128) u16 sA[2][4096];
  __shared__ __align__(128) u16 sB[2][4096];
  const int m0 = blockIdx.x*64, n0 = blockIdx.y*64;
  const int tid = threadIdx.x, w = tid>>6, lane = tid&63;
  const int wr = w>>1, wc = w&1;
  const int lr = lane&15, lg = lane>>4;
  f32x4 acc[2][2] = {};
  stage_gemm(A, m0, 0, sA[0], tid);
  stage_gemm(W, n0, 0, sB[0], tid);
  int buf = 0;
  for (int kt=0; kt<8; ++kt){
    __syncthreads();
    if (kt < 7){
      stage_gemm(A, m0, (kt+1)*64, sA[buf^1], tid);
      stage_gemm(W, n0, (kt+1)*64, sB[buf^1], tid);
    }
    #pragma unroll
    for (int ks=0; ks<2; ++ks){
      bf16x8 af[2], bfr[2];
      #pragma unroll
      for (int mi=0; mi<2; ++mi){
        const int r = wr*32 + mi*16 + lr;
        af[mi] = *(const bf16x8*)(&sA[buf][(r*64 + ks*32 + lg*8) ^ ((r&7)<<3)]);
      }
      #pragma unroll
      for (int nj=0; nj<2; ++nj){
        const int r = wc*32 + nj*16 + lr;
        bfr[nj] = *(const bf16x8*)(&sB[buf][(r*64 + ks*32 + lg*8) ^ ((r&7)<<3)]);
      }
      #pragma unroll
      for (int mi=0; mi<2; ++mi)
        #pragma unroll
        for (int nj=0; nj<2; ++nj)
          acc[mi][nj] = MFMA16(af[mi], bfr[nj], acc[mi][nj]);
    }
    buf ^= 1;
  }
  #pragma unroll
  for (int mi=0; mi<2; ++mi)
    #pragma unroll
    for (int nj=0; nj<2; ++nj)
      #pragma unroll
      for (int r=0; r<4; ++r){
        const int m = m0 + wr*32 + mi*16 + lg*4 + r;
        const int n = n0 + wc*32 + nj*16 + lr;
        const int bb = m>>10, l = m&1023, hh = n>>6, d = n&63;
        const int bh = bb*NHEAD + hh;
        const int t = l>>6;
        const u16 val = f2bf(acc[mi][nj][r]);
        {  // K/Q fragment position
          const int rr = l&63;
          const int fnj = rr>>4, flr = rr&15;
          const int fks = d>>5, flg = (d>>3)&3, fj = d&7;
          Kf[(size_t)(bh*16 + t)*4096 + (fks*4+fnj)*512 + (flg*16+flr)*8 + fj] = val;
        }
        {  // V fragment position
          const int ll = l&63;
          const int fks = ll>>5, flg = (ll>>3)&3, fj = ll&7;
          const int fdj = d>>4, flr = d&15;
          Vf[(size_t)(bh*16 + t)*4096 + (fks*4+fdj)*512 + (flg*16+flr)*8 + fj] = val;
        }
      }
}

// ---------------- attention: split-K (4 k-tiles/wave), L2-direct, tree merge ----
__global__ __launch_bounds__(256,4) void attn_k(const u16* __restrict__ kf,
                                                const u16* __restrict__ vf,
                                                u16* __restrict__ ao){
  // during loop: 4 waves x 4 groups x 2KB wave-private P. after: 2 f32 merge regions
  __shared__ __align__(16) u16 sPm[16640];
  const int bid = blockIdx.x;
  const int qt = bid >> 6, bh = bid & 63;     // XCD = bid%8 = bh%8 -> K/V L2-resident
  const int b = bh >> 3, h = bh & 7;
  const u16* Kf = kf + (size_t)bh*16*4096;
  const u16* Vf = vf + (size_t)bh*16*4096;
  const int tid = threadIdx.x, w = tid>>6, lane = tid&63;
  const int lr = lane&15, lg = lane>>4;

  // Q fragments for 4 groups (the 4 nj-subtiles of q-tile qt); pre-scaled
  bf16x8 aq[4][2];
  #pragma unroll
  for (int g=0; g<4; ++g)
    #pragma unroll
    for (int ks=0; ks<2; ++ks){
      u16x8 v = *(const u16x8*)(Kf + (size_t)qt*4096 + (ks*4+g)*512 + lane*8);
      bf16x8 t;
      #pragma unroll
      for (int j=0;j<8;j++) t[j] = (short)f2bf(bf2f(v[j])*0.18033688f);
      aq[g][ks] = t;
    }

  f32x4 o[4][4] = {};
  float lsum[4][4] = {};

  // wave w owns k-tiles {w, w+4, w+8, w+12}: no barriers, no cross-wave K/V reuse
  for (int t=0; t<4; ++t){
    const int kt = w + t*4;
    const u16* Kt = Kf + (size_t)kt*4096;
    const u16* Vt = Vf + (size_t)kt*4096;
    bf16x8 bk[2][4];
    #pragma unroll
    for (int ks=0; ks<2; ++ks)
      #pragma unroll
      for (int nj=0; nj<4; ++nj)
        bk[ks][nj] = *(const bf16x8*)(Kt + (ks*4+nj)*512 + lane*8);
    #pragma unroll
    for (int g=0; g<4; ++g){
      f32x4 sc[4] = {};
      __builtin_amdgcn_s_setprio(1);
      #pragma unroll
      for (int ks=0; ks<2; ++ks)
        #pragma unroll
        for (int nj=0; nj<4; ++nj)
          sc[nj] = MFMA16(aq[g][ks], bk[ks][nj], sc[nj]);
      __builtin_amdgcn_s_setprio(0);
      const int wp = (w*4+g)*1024;
      #pragma unroll
      for (int nj=0; nj<4; ++nj){
        #pragma unroll
        for (int r=0; r<4; ++r){
          const float p = __builtin_amdgcn_exp2f(sc[nj][r]);
          const unsigned pu = __float_as_uint(p) & 0xFFFF0000u;
          lsum[g][r] += __uint_as_float(pu);
          const int prow = lg*4 + r;
          sPm[wp + ((prow*64 + nj*16 + lr) ^ ((prow&7)<<3))] = (u16)(pu>>16);
        }
      }
    }
    asm volatile("s_waitcnt lgkmcnt(0)" ::: "memory");
    bf16x8 bv[2][4];
    #pragma unroll
    for (int ks=0; ks<2; ++ks)
      #pragma unroll
      for (int dj=0; dj<4; ++dj)
        bv[ks][dj] = *(const bf16x8*)(Vt + (ks*4+dj)*512 + lane*8);
    __builtin_amdgcn_s_setprio(1);
    #pragma unroll
    for (int g=0; g<4; ++g){
      const int wp = (w*4+g)*1024;
      #pragma unroll
      for (int ks=0; ks<2; ++ks){
        bf16x8 pa = *(const bf16x8*)(&sPm[wp + ((lr*64 + ks*32 + lg*8) ^ ((lr&7)<<3))]);
        #pragma unroll
        for (int dj=0; dj<4; ++dj)
          o[g][dj] = MFMA16(pa, bv[ks][dj], o[g][dj]);
      }
    }
    __builtin_amdgcn_s_setprio(0);
  }

  // reduce lsum across the 16 lanes sharing lg (per wave, before merge)
  #pragma unroll
  for (int g=0; g<4; ++g)
    #pragma unroll
    for (int r=0; r<4; ++r){
      float s = lsum[g][r];
      s += __shfl_xor(s,1); s += __shfl_xor(s,2);
      s += __shfl_xor(s,4); s += __shfl_xor(s,8);
      lsum[g][r] = s;
    }

  __syncthreads();                    // all P use complete; repurpose LDS for merge
  float* mrg = (float*)sPm;           // region r at r*4160 floats: o[16][256] + lsum[64]
  if (w & 1){
    float* R = mrg + (w>>1)*4160;
    #pragma unroll
    for (int g=0; g<4; ++g){
      #pragma unroll
      for (int dj=0; dj<4; ++dj)
        *(f32x4*)&R[(g*4+dj)*256 + lane*4] = o[g][dj];
      if (lr == 0)
        #pragma unroll
        for (int r=0; r<4; ++r) R[4096 + g*16 + lg*4 + r] = lsum[g][r];
    }
  }
  __syncthreads();
  if (!(w & 1)){
    float* R = mrg + (w>>1)*4160;
    #pragma unroll
    for (int g=0; g<4; ++g){
      #pragma unroll
      for (int dj=0; dj<4; ++dj)
        o[g][dj] += *(const f32x4*)&R[(g*4+dj)*256 + lane*4];
      #pragma unroll
      for (int r=0; r<4; ++r) lsum[g][r] += R[4096 + g*16 + lg*4 + r];
    }
  }
  if (w == 2){
    float* R = mrg + 4160;
    #pragma unroll
    for (int g=0; g<4; ++g){
      #pragma unroll
      for (int dj=0; dj<4; ++dj)
        *(f32x4*)&R[(g*4+dj)*256 + lane*4] = o[g][dj];
      if (lr == 0)
        #pragma unroll
        for (int r=0; r<4; ++r) R[4096 + g*16 + lg*4 + r] = lsum[g][r];
    }
  }
  __syncthreads();
  if (w == 0){
    float* R = mrg + 4160;
    #pragma unroll
    for (int g=0; g<4; ++g){
      #pragma unroll
      for (int dj=0; dj<4; ++dj)
        o[g][dj] += *(const f32x4*)&R[(g*4+dj)*256 + lane*4];
      #pragma unroll
      for (int r=0; r<4; ++r) lsum[g][r] += R[4096 + g*16 + lg*4 + r];
    }
    #pragma unroll
    for (int g=0; g<4; ++g){
      float inv[4];
      #pragma unroll
      for (int r=0; r<4; ++r) inv[r] = __builtin_amdgcn_rcpf(lsum[g][r]);
      const int i0 = qt*64 + g*16;
      #pragma unroll
      for (int dj=0; dj<4; ++dj)
        #pragma unroll
        for (int r=0; r<4; ++r){
          const int l = i0 + lg*4 + r;
          const int d = dj*16 + lr;
          ao[((size_t)(b*LTOK + l))*DMODEL + h*DHEAD + d] = f2bf(o[g][dj][r]*inv[r]);
        }
    }
  }
}

// ---------------- FC projection + bias + residual -------------------------------
__global__ __launch_bounds__(256) void fc_gemm(const u16* __restrict__ A,
                                               const u16* __restrict__ W,
                                               const float* __restrict__ bias,
                                               const u16* __restrict__ resid,
                                               u16* __restrict__ Y){
  __shared__ __align__(128) u16 sA[2][4096];
  __shared__ __align__(128) u16 sB[2][4096];
  const int m0 = blockIdx.x*64, n0 = blockIdx.y*64;
  const int tid = threadIdx.x, w = tid>>6, lane = tid&63;
  const int wr = w>>1, wc = w&1;
  const int lr = lane&15, lg = lane>>4;
  f32x4 acc[2][2] = {};
  stage_gemm(A, m0, 0, sA[0], tid);
  stage_gemm(W, n0, 0, sB[0], tid);
  int buf = 0;
  for (int kt=0; kt<8; ++kt){
    __syncthreads();
    if (kt < 7){
      stage_gemm(A, m0, (kt+1)*64, sA[buf^1], tid);
      stage_gemm(W, n0, (kt+1)*64, sB[buf^1], tid);
    }
    #pragma unroll
    for (int ks=0; ks<2; ++ks){
      bf16x8 af[2], bfr[2];
      #pragma unroll
      for (int mi=0; mi<2; ++mi){
        const int r = wr*32 + mi*16 + lr;
        af[mi] = *(const bf16x8*)(&sA[buf][(r*64 + ks*32 + lg*8) ^ ((r&7)<<3)]);
      }
      #pragma unroll
      for (int nj=0; nj<2; ++nj){
        const int r = wc*32 + nj*16 + lr;
        bfr[nj] = *(const bf16x8*)(&sB[buf][(r*64 + ks*32 + lg*8) ^ ((r&7)<<3)]);
      }
      #pragma unroll
      for (int mi=0; mi<2; ++mi)
        #pragma unroll
        for (int nj=0; nj<2; ++nj)
          acc[mi][nj] = MFMA16(af[mi], bfr[nj], acc[mi][nj]);
    }
    buf ^= 1;
  }
  #pragma unroll
  for (int mi=0; mi<2; ++mi)
    #pragma unroll
    for (int nj=0; nj<2; ++nj)
      #pragma unroll
      for (int r=0; r<4; ++r){
        const int m = m0 + wr*32 + mi*16 + lg*4 + r;
        const int n = n0 + wc*32 + nj*16 + lr;
        const float val = acc[mi][nj][r] + bias[n] + bf2f(resid[(size_t)m*DMODEL+n]);
        Y[(size_t)m*DMODEL+n] = f2bf(val);
      }
}

// ---------------- LayerNorm over 512, one wave per row; fp32 out ----------------
__global__ __launch_bounds__(256) void ln_k(const u16* __restrict__ Y,
                                            const float* __restrict__ gamma,
                                            const float* __restrict__ beta,
                                            float* __restrict__ out){
  const int row = blockIdx.x*4 + (threadIdx.x>>6);
  const int lane = threadIdx.x&63;
  const u16* yr = Y + (size_t)row*DMODEL;
  u16x8 v = *(const u16x8*)(yr + lane*8);
  float x[8]; float s=0.f, sq=0.f;
  #pragma unroll
  for (int j=0;j<8;j++){ x[j]=bf2f(v[j]); s+=x[j]; sq+=x[j]*x[j]; }
  #pragma unroll
  for (int mk=1; mk<64; mk<<=1){ s += __shfl_xor(s,mk); sq += __shfl_xor(sq,mk); }
  const float mean = s*(1.f/DMODEL);
  float var = sq*(1.f/DMODEL) - mean*mean;
  const float rstd = rsqrtf(var + 1e-5f);
  float* po = out + (size_t)row*DMODEL + lane*8;
  #pragma unroll
  for (int j=0;j<8;j++){
    const int c = lane*8+j;
    po[j] = (x[j]-mean)*rstd*gamma[c] + beta[c];
  }
}

extern "C" void kernel_launch(void* const* d_in, const int* in_sizes, int n_in,
                              void* d_out, int out_size, void* d_ws, size_t ws_size,
                              hipStream_t stream){
  (void)in_sizes; (void)n_in; (void)out_size; (void)ws_size;
  const float* q      = (const float*)d_in[0];
  const float* w_qkvs = (const float*)d_in[1];
  const float* fc_w   = (const float*)d_in[2];
  const float* fc_b   = (const float*)d_in[3];
  const float* ln_g   = (const float*)d_in[4];
  const float* ln_b   = (const float*)d_in[5];
  float* out = (float*)d_out;
  char* ws = (char*)d_ws;
  u16* x_rm  = (u16*)(ws);                 // [8192][512] bf16
  u16* kfb   = (u16*)(ws + 8388608);       // fragment-major K/Q tiles
  u16* vfb   = (u16*)(ws + 16777216);      // fragment-major V tiles
  u16* ao    = (u16*)(ws + 25165824);      // [8192][512]
  u16* wqkvb = (u16*)(ws + 33554432);
  u16* wfcb  = (u16*)(ws + 34078720);
  u16* y0    = kfb;                        // reuse after attention

  convert_k<<<128,256,0,stream>>>(w_qkvs, wqkvb, DMODEL*DMODEL);
  convert_k<<<128,256,0,stream>>>(fc_w,   wfcb,  DMODEL*DMODEL);
  transpose_f2b<<<dim3(8,16,BATCH),256,0,stream>>>(q, x_rm, DMODEL, LTOK);
  qkv_gemm<<<dim3(128,8),256,0,stream>>>(x_rm, wqkvb, kfb, vfb);
  attn_k<<<1024,256,0,stream>>>(kfb, vfb, ao);
  fc_gemm<<<dim3(128,8),256,0,stream>>>(ao, wfcb, fc_b, x_rm, y0);
  ln_k<<<2048,256,0,stream>>>(y0, ln_g, ln_b, out);
}

// Round 12
// 76.622 us; speedup vs baseline: 1.8970x; 1.8970x over previous
//
#include <hip/hip_runtime.h>
#include <stdint.h>

#define BATCH 8
#define LTOK 1024
#define DMODEL 512
#define NHEAD 8
#define DHEAD 64

typedef unsigned short u16;
typedef u16 u16x8 __attribute__((ext_vector_type(8)));
typedef short bf16x8 __attribute__((ext_vector_type(8)));
typedef float f32x4 __attribute__((ext_vector_type(4)));

#define MFMA16(a,b,c) __builtin_amdgcn_mfma_f32_16x16x32_bf16((a),(b),(c),0,0,0)

__device__ __forceinline__ float bf2f(u16 x){
  union{unsigned u; float f;} v; v.u = ((unsigned)x)<<16; return v.f;
}
__device__ __forceinline__ u16 f2bf(float f){
  union{float f; unsigned u;} v; v.f = f;
  unsigned r = v.u + 0x7fffu + ((v.u>>16)&1u);
  return (u16)(r>>16);
}

__device__ __forceinline__ void gload_lds16(const u16* g, u16* l){
  __builtin_amdgcn_global_load_lds(
      (const __attribute__((address_space(1))) void*)g,
      (__attribute__((address_space(3))) void*)l,
      16, 0, 0);
}

// ---------------- fp32 -> bf16 convert, both weight matrices in one launch ------
__global__ __launch_bounds__(256) void convert2_k(const float* __restrict__ s0,
                                                  u16* __restrict__ d0,
                                                  const float* __restrict__ s1,
                                                  u16* __restrict__ d1){
  const int blk = blockIdx.x;
  const float* src = (blk < 128) ? s0 : s1;
  u16* dst        = (blk < 128) ? d0 : d1;
  const int i = (((blk & 127)*256) + threadIdx.x)*8;
  u16x8 v;
  #pragma unroll
  for (int j=0;j<8;j++) v[j] = f2bf(src[i+j]);
  *(u16x8*)(dst + i) = v;
}

// ---------------- 64x64 tiled transpose fp32->bf16: dst[c][r] = src[r][c] -------
__global__ __launch_bounds__(256) void transpose_f2b(const float* __restrict__ src,
                                                     u16* __restrict__ dst,
                                                     int R, int C){
  __shared__ __align__(16) u16 t[64][72];
  const int b  = blockIdx.z;
  const int r0 = blockIdx.x*64, c0 = blockIdx.y*64;
  const float* s = src + (size_t)b*R*C;
  u16* d         = dst + (size_t)b*R*C;
  const int tid = threadIdx.x;
  const int row = tid>>3, ch = (tid&7)*8;
  #pragma unroll
  for (int rr=0; rr<64; rr+=32){
    const float* p = s + (size_t)(r0+row+rr)*C + c0 + ch;
    u16x8 v;
    #pragma unroll
    for (int j=0;j<8;j++) v[j] = f2bf(p[j]);
    *(u16x8*)&t[row+rr][ch] = v;
  }
  __syncthreads();
  #pragma unroll
  for (int rr=0; rr<64; rr+=32){
    const int dr = row+rr;
    u16x8 v;
    #pragma unroll
    for (int j=0;j<8;j++) v[j] = t[ch+j][dr];
    *(u16x8*)(d + (size_t)(c0+dr)*R + r0 + ch) = v;
  }
}

// stage a 64x64 bf16 tile into linear LDS with the read-swizzle pre-applied to
// the source k-chunk (rule 21: filler granule (r, cc^(r&7)) holds A[r][cc*8])
__device__ __forceinline__ void stage_gemm(const u16* __restrict__ src,
                                           int row0, int k0, u16* lds, int tid){
  #pragma unroll
  for (int s2=0; s2<2; ++s2){
    const int slot = tid + s2*256;
    const int row = slot>>3, ch8 = slot&7;
    const int k = k0 + ((ch8 ^ (row&7))<<3);
    gload_lds16(src + (size_t)(row0+row)*DMODEL + k, lds + slot*8);
  }
}

// ---------------- QKV projection -> MFMA-fragment-major K/Q and V^T tiles -------
// Kf[bh][t][frag=ks*4+nj][lane=lg*16+lr][j]  holds K[t*64+nj*16+lr][ks*32+lg*8+j]
// Vf[bh][t][frag=ks*4+dj][lane=lg*16+lr][j]  holds V[t*64+ks*32+lg*8+j][dj*16+lr]
__global__ __launch_bounds__(256) void qkv_gemm(const u16* __restrict__ A,
                                                const u16* __restrict__ W,
                                                u16* __restrict__ Kf,
                                                u16* __restrict__ Vf){
  __shared__ __align__(128) u16 sA[2][4096];
  __shared__ __align__(128) u16 sB[2][4096];
  const int m0 = blockIdx.x*64, n0 = blockIdx.y*64;
  const int tid = threadIdx.x, w = tid>>6, lane = tid&63;
  const int wr = w>>1, wc = w&1;
  const int lr = lane&15, lg = lane>>4;
  f32x4 acc[2][2] = {};
  stage_gemm(A, m0, 0, sA[0], tid);
  stage_gemm(W, n0, 0, sB[0], tid);
  int buf = 0;
  for (int kt=0; kt<8; ++kt){
    __syncthreads();
    if (kt < 7){
      stage_gemm(A, m0, (kt+1)*64, sA[buf^1], tid);
      stage_gemm(W, n0, (kt+1)*64, sB[buf^1], tid);
    }
    #pragma unroll
    for (int ks=0; ks<2; ++ks){
      bf16x8 af[2], bfr[2];
      #pragma unroll
      for (int mi=0; mi<2; ++mi){
        const int r = wr*32 + mi*16 + lr;
        af[mi] = *(const bf16x8*)(&sA[buf][(r*64 + ks*32 + lg*8) ^ ((r&7)<<3)]);
      }
      #pragma unroll
      for (int nj=0; nj<2; ++nj){
        const int r = wc*32 + nj*16 + lr;
        bfr[nj] = *(const bf16x8*)(&sB[buf][(r*64 + ks*32 + lg*8) ^ ((r&7)<<3)]);
      }
      #pragma unroll
      for (int mi=0; mi<2; ++mi)
        #pragma unroll
        for (int nj=0; nj<2; ++nj)
          acc[mi][nj] = MFMA16(af[mi], bfr[nj], acc[mi][nj]);
    }
    buf ^= 1;
  }
  #pragma unroll
  for (int mi=0; mi<2; ++mi)
    #pragma unroll
    for (int nj=0; nj<2; ++nj)
      #pragma unroll
      for (int r=0; r<4; ++r){
        const int m = m0 + wr*32 + mi*16 + lg*4 + r;
        const int n = n0 + wc*32 + nj*16 + lr;
        const int bb = m>>10, l = m&1023, hh = n>>6, d = n&63;
        const int bh = bb*NHEAD + hh;
        const int t = l>>6;
        const u16 val = f2bf(acc[mi][nj][r]);
        {  // K/Q fragment position
          const int rr = l&63;
          const int fnj = rr>>4, flr = rr&15;
          const int fks = d>>5, flg = (d>>3)&3, fj = d&7;
          Kf[(size_t)(bh*16 + t)*4096 + (fks*4+fnj)*512 + (flg*16+flr)*8 + fj] = val;
        }
        {  // V fragment position
          const int ll = l&63;
          const int fks = ll>>5, flg = (ll>>3)&3, fj = ll&7;
          const int fdj = d>>4, flr = d&15;
          Vf[(size_t)(bh*16 + t)*4096 + (fks*4+fdj)*512 + (flg*16+flr)*8 + fj] = val;
        }
      }
}

// ---------------- attention: split-K (4 k-tiles/wave), L2-direct, tree merge ----
// launch_bounds(256,2): 2 blk/CU, VGPR cap 256 -> NO spill (round-11 bug was (,4) -> 64 VGPR cap)
__global__ __launch_bounds__(256,2) void attn_k(const u16* __restrict__ kf,
                                                const u16* __restrict__ vf,
                                                u16* __restrict__ ao){
  // during loop: 4 waves x 4 groups x 2KB wave-private P. after: 2 f32 merge regions
  __shared__ __align__(16) u16 sPm[16640];
  const int bid = blockIdx.x;
  const int qt = bid >> 6, bh = bid & 63;     // XCD = bid%8 = bh%8 -> K/V L2-resident
  const int b = bh >> 3, h = bh & 7;
  const u16* Kf = kf + (size_t)bh*16*4096;
  const u16* Vf = vf + (size_t)bh*16*4096;
  const int tid = threadIdx.x, w = tid>>6, lane = tid&63;
  const int lr = lane&15, lg = lane>>4;

  // Q fragments for 4 groups (the 4 nj-subtiles of q-tile qt); pre-scaled
  bf16x8 aq[4][2];
  #pragma unroll
  for (int g=0; g<4; ++g)
    #pragma unroll
    for (int ks=0; ks<2; ++ks){
      u16x8 v = *(const u16x8*)(Kf + (size_t)qt*4096 + (ks*4+g)*512 + lane*8);
      bf16x8 t;
      #pragma unroll
      for (int j=0;j<8;j++) t[j] = (short)f2bf(bf2f(v[j])*0.18033688f);
      aq[g][ks] = t;
    }

  f32x4 o[4][4] = {};
  float lsum[4][4] = {};

  // wave w owns k-tiles {w, w+4, w+8, w+12}: no barriers, no cross-wave K/V reuse
  for (int t=0; t<4; ++t){
    const int kt = w + t*4;
    const u16* Kt = Kf + (size_t)kt*4096;
    const u16* Vt = Vf + (size_t)kt*4096;
    bf16x8 bk[2][4];
    #pragma unroll
    for (int ks=0; ks<2; ++ks)
      #pragma unroll
      for (int nj=0; nj<4; ++nj)
        bk[ks][nj] = *(const bf16x8*)(Kt + (ks*4+nj)*512 + lane*8);
    #pragma unroll
    for (int g=0; g<4; ++g){
      f32x4 sc[4] = {};
      __builtin_amdgcn_s_setprio(1);
      #pragma unroll
      for (int ks=0; ks<2; ++ks)
        #pragma unroll
        for (int nj=0; nj<4; ++nj)
          sc[nj] = MFMA16(aq[g][ks], bk[ks][nj], sc[nj]);
      __builtin_amdgcn_s_setprio(0);
      const int wp = (w*4+g)*1024;
      #pragma unroll
      for (int nj=0; nj<4; ++nj){
        #pragma unroll
        for (int r=0; r<4; ++r){
          const float p = __builtin_amdgcn_exp2f(sc[nj][r]);
          const unsigned pu = __float_as_uint(p) & 0xFFFF0000u;
          lsum[g][r] += __uint_as_float(pu);
          const int prow = lg*4 + r;
          sPm[wp + ((prow*64 + nj*16 + lr) ^ ((prow&7)<<3))] = (u16)(pu>>16);
        }
      }
    }
    asm volatile("s_waitcnt lgkmcnt(0)" ::: "memory");
    bf16x8 bv[2][4];
    #pragma unroll
    for (int ks=0; ks<2; ++ks)
      #pragma unroll
      for (int dj=0; dj<4; ++dj)
        bv[ks][dj] = *(const bf16x8*)(Vt + (ks*4+dj)*512 + lane*8);
    __builtin_amdgcn_s_setprio(1);
    #pragma unroll
    for (int g=0; g<4; ++g){
      const int wp = (w*4+g)*1024;
      #pragma unroll
      for (int ks=0; ks<2; ++ks){
        bf16x8 pa = *(const bf16x8*)(&sPm[wp + ((lr*64 + ks*32 + lg*8) ^ ((lr&7)<<3))]);
        #pragma unroll
        for (int dj=0; dj<4; ++dj)
          o[g][dj] = MFMA16(pa, bv[ks][dj], o[g][dj]);
      }
    }
    __builtin_amdgcn_s_setprio(0);
  }

  // reduce lsum across the 16 lanes sharing lg (per wave, before merge)
  #pragma unroll
  for (int g=0; g<4; ++g)
    #pragma unroll
    for (int r=0; r<4; ++r){
      float s = lsum[g][r];
      s += __shfl_xor(s,1); s += __shfl_xor(s,2);
      s += __shfl_xor(s,4); s += __shfl_xor(s,8);
      lsum[g][r] = s;
    }

  __syncthreads();                    // all P use complete; repurpose LDS for merge
  float* mrg = (float*)sPm;           // region r at r*4160 floats: o[16][256] + lsum[64]
  if (w & 1){
    float* R = mrg + (w>>1)*4160;
    #pragma unroll
    for (int g=0; g<4; ++g){
      #pragma unroll
      for (int dj=0; dj<4; ++dj)
        *(f32x4*)&R[(g*4+dj)*256 + lane*4] = o[g][dj];
      if (lr == 0)
        #pragma unroll
        for (int r=0; r<4; ++r) R[4096 + g*16 + lg*4 + r] = lsum[g][r];
    }
  }
  __syncthreads();
  if (!(w & 1)){
    float* R = mrg + (w>>1)*4160;
    #pragma unroll
    for (int g=0; g<4; ++g){
      #pragma unroll
      for (int dj=0; dj<4; ++dj)
        o[g][dj] += *(const f32x4*)&R[(g*4+dj)*256 + lane*4];
      #pragma unroll
      for (int r=0; r<4; ++r) lsum[g][r] += R[4096 + g*16 + lg*4 + r];
    }
  }
  if (w == 2){
    float* R = mrg + 4160;
    #pragma unroll
    for (int g=0; g<4; ++g){
      #pragma unroll
      for (int dj=0; dj<4; ++dj)
        *(f32x4*)&R[(g*4+dj)*256 + lane*4] = o[g][dj];
      if (lr == 0)
        #pragma unroll
        for (int r=0; r<4; ++r) R[4096 + g*16 + lg*4 + r] = lsum[g][r];
    }
  }
  __syncthreads();
  if (w == 0){
    float* R = mrg + 4160;
    #pragma unroll
    for (int g=0; g<4; ++g){
      #pragma unroll
      for (int dj=0; dj<4; ++dj)
        o[g][dj] += *(const f32x4*)&R[(g*4+dj)*256 + lane*4];
      #pragma unroll
      for (int r=0; r<4; ++r) lsum[g][r] += R[4096 + g*16 + lg*4 + r];
    }
    #pragma unroll
    for (int g=0; g<4; ++g){
      float inv[4];
      #pragma unroll
      for (int r=0; r<4; ++r) inv[r] = __builtin_amdgcn_rcpf(lsum[g][r]);
      const int i0 = qt*64 + g*16;
      #pragma unroll
      for (int dj=0; dj<4; ++dj)
        #pragma unroll
        for (int r=0; r<4; ++r){
          const int l = i0 + lg*4 + r;
          const int d = dj*16 + lr;
          ao[((size_t)(b*LTOK + l))*DMODEL + h*DHEAD + d] = f2bf(o[g][dj][r]*inv[r]);
        }
    }
  }
}

// ---------------- FC projection + bias + residual -------------------------------
__global__ __launch_bounds__(256) void fc_gemm(const u16* __restrict__ A,
                                               const u16* __restrict__ W,
                                               const float* __restrict__ bias,
                                               const u16* __restrict__ resid,
                                               u16* __restrict__ Y){
  __shared__ __align__(128) u16 sA[2][4096];
  __shared__ __align__(128) u16 sB[2][4096];
  const int m0 = blockIdx.x*64, n0 = blockIdx.y*64;
  const int tid = threadIdx.x, w = tid>>6, lane = tid&63;
  const int wr = w>>1, wc = w&1;
  const int lr = lane&15, lg = lane>>4;
  f32x4 acc[2][2] = {};
  stage_gemm(A, m0, 0, sA[0], tid);
  stage_gemm(W, n0, 0, sB[0], tid);
  int buf = 0;
  for (int kt=0; kt<8; ++kt){
    __syncthreads();
    if (kt < 7){
      stage_gemm(A, m0, (kt+1)*64, sA[buf^1], tid);
      stage_gemm(W, n0, (kt+1)*64, sB[buf^1], tid);
    }
    #pragma unroll
    for (int ks=0; ks<2; ++ks){
      bf16x8 af[2], bfr[2];
      #pragma unroll
      for (int mi=0; mi<2; ++mi){
        const int r = wr*32 + mi*16 + lr;
        af[mi] = *(const bf16x8*)(&sA[buf][(r*64 + ks*32 + lg*8) ^ ((r&7)<<3)]);
      }
      #pragma unroll
      for (int nj=0; nj<2; ++nj){
        const int r = wc*32 + nj*16 + lr;
        bfr[nj] = *(const bf16x8*)(&sB[buf][(r*64 + ks*32 + lg*8) ^ ((r&7)<<3)]);
      }
      #pragma unroll
      for (int mi=0; mi<2; ++mi)
        #pragma unroll
        for (int nj=0; nj<2; ++nj)
          acc[mi][nj] = MFMA16(af[mi], bfr[nj], acc[mi][nj]);
    }
    buf ^= 1;
  }
  #pragma unroll
  for (int mi=0; mi<2; ++mi)
    #pragma unroll
    for (int nj=0; nj<2; ++nj)
      #pragma unroll
      for (int r=0; r<4; ++r){
        const int m = m0 + wr*32 + mi*16 + lg*4 + r;
        const int n = n0 + wc*32 + nj*16 + lr;
        const float val = acc[mi][nj][r] + bias[n] + bf2f(resid[(size_t)m*DMODEL+n]);
        Y[(size_t)m*DMODEL+n] = f2bf(val);
      }
}

// ---------------- LayerNorm over 512, one wave per row; fp32 out ----------------
__global__ __launch_bounds__(256) void ln_k(const u16* __restrict__ Y,
                                            const float* __restrict__ gamma,
                                            const float* __restrict__ beta,
                                            float* __restrict__ out){
  const int row = blockIdx.x*4 + (threadIdx.x>>6);
  const int lane = threadIdx.x&63;
  const u16* yr = Y + (size_t)row*DMODEL;
  u16x8 v = *(const u16x8*)(yr + lane*8);
  float x[8]; float s=0.f, sq=0.f;
  #pragma unroll
  for (int j=0;j<8;j++){ x[j]=bf2f(v[j]); s+=x[j]; sq+=x[j]*x[j]; }
  #pragma unroll
  for (int mk=1; mk<64; mk<<=1){ s += __shfl_xor(s,mk); sq += __shfl_xor(sq,mk); }
  const float mean = s*(1.f/DMODEL);
  float var = sq*(1.f/DMODEL) - mean*mean;
  const float rstd = rsqrtf(var + 1e-5f);
  float* po = out + (size_t)row*DMODEL + lane*8;
  #pragma unroll
  for (int j=0;j<8;j++){
    const int c = lane*8+j;
    po[j] = (x[j]-mean)*rstd*gamma[c] + beta[c];
  }
}

extern "C" void kernel_launch(void* const* d_in, const int* in_sizes, int n_in,
                              void* d_out, int out_size, void* d_ws, size_t ws_size,
                              hipStream_t stream){
  (void)in_sizes; (void)n_in; (void)out_size; (void)ws_size;
  const float* q      = (const float*)d_in[0];
  const float* w_qkvs = (const float*)d_in[1];
  const float* fc_w   = (const float*)d_in[2];
  const float* fc_b   = (const float*)d_in[3];
  const float* ln_g   = (const float*)d_in[4];
  const float* ln_b   = (const float*)d_in[5];
  float* out = (float*)d_out;
  char* ws = (char*)d_ws;
  u16* x_rm  = (u16*)(ws);                 // [8192][512] bf16
  u16* kfb   = (u16*)(ws + 8388608);       // fragment-major K/Q tiles
  u16* vfb   = (u16*)(ws + 16777216);      // fragment-major V tiles
  u16* ao    = (u16*)(ws + 25165824);      // [8192][512]
  u16* wqkvb = (u16*)(ws + 33554432);
  u16* wfcb  = (u16*)(ws + 34078720);
  u16* y0    = kfb;                        // reuse after attention

  convert2_k<<<256,256,0,stream>>>(w_qkvs, wqkvb, fc_w, wfcb);
  transpose_f2b<<<dim3(8,16,BATCH),256,0,stream>>>(q, x_rm, DMODEL, LTOK);
  qkv_gemm<<<dim3(128,8),256,0,stream>>>(x_rm, wqkvb, kfb, vfb);
  attn_k<<<1024,256,0,stream>>>(kfb, vfb, ao);
  fc_gemm<<<dim3(128,8),256,0,stream>>>(ao, wfcb, fc_b, x_rm, y0);
  ln_k<<<2048,256,0,stream>>>(y0, ln_g, ln_b, out);
}

// Round 13
// 76.108 us; speedup vs baseline: 1.9098x; 1.0067x over previous
//
#include <hip/hip_runtime.h>
#include <stdint.h>

#define BATCH 8
#define LTOK 1024
#define DMODEL 512
#define NHEAD 8
#define DHEAD 64

typedef unsigned short u16;
typedef u16 u16x4 __attribute__((ext_vector_type(4)));
typedef u16 u16x8 __attribute__((ext_vector_type(8)));
typedef short bf16x8 __attribute__((ext_vector_type(8)));
typedef float f32x4 __attribute__((ext_vector_type(4)));

#define MFMA16(a,b,c) __builtin_amdgcn_mfma_f32_16x16x32_bf16((a),(b),(c),0,0,0)

__device__ __forceinline__ float bf2f(u16 x){
  union{unsigned u; float f;} v; v.u = ((unsigned)x)<<16; return v.f;
}
__device__ __forceinline__ u16 f2bf(float f){
  union{float f; unsigned u;} v; v.f = f;
  unsigned r = v.u + 0x7fffu + ((v.u>>16)&1u);
  return (u16)(r>>16);
}

__device__ __forceinline__ void gload_lds16(const u16* g, u16* l){
  __builtin_amdgcn_global_load_lds(
      (const __attribute__((address_space(1))) void*)g,
      (__attribute__((address_space(3))) void*)l,
      16, 0, 0);
}

// ---------------- fp32 -> bf16 convert, both weight matrices in one launch ------
__global__ __launch_bounds__(256) void convert2_k(const float* __restrict__ s0,
                                                  u16* __restrict__ d0,
                                                  const float* __restrict__ s1,
                                                  u16* __restrict__ d1){
  const int blk = blockIdx.x;
  const float* src = (blk < 128) ? s0 : s1;
  u16* dst        = (blk < 128) ? d0 : d1;
  const int i = (((blk & 127)*256) + threadIdx.x)*8;
  u16x8 v;
  #pragma unroll
  for (int j=0;j<8;j++) v[j] = f2bf(src[i+j]);
  *(u16x8*)(dst + i) = v;
}

// ---------------- 64x64 tiled transpose fp32->bf16: dst[c][r] = src[r][c] -------
__global__ __launch_bounds__(256) void transpose_f2b(const float* __restrict__ src,
                                                     u16* __restrict__ dst,
                                                     int R, int C){
  __shared__ __align__(16) u16 t[64][72];
  const int b  = blockIdx.z;
  const int r0 = blockIdx.x*64, c0 = blockIdx.y*64;
  const float* s = src + (size_t)b*R*C;
  u16* d         = dst + (size_t)b*R*C;
  const int tid = threadIdx.x;
  const int row = tid>>3, ch = (tid&7)*8;
  #pragma unroll
  for (int rr=0; rr<64; rr+=32){
    const float* p = s + (size_t)(r0+row+rr)*C + c0 + ch;
    u16x8 v;
    #pragma unroll
    for (int j=0;j<8;j++) v[j] = f2bf(p[j]);
    *(u16x8*)&t[row+rr][ch] = v;
  }
  __syncthreads();
  #pragma unroll
  for (int rr=0; rr<64; rr+=32){
    const int dr = row+rr;
    u16x8 v;
    #pragma unroll
    for (int j=0;j<8;j++) v[j] = t[ch+j][dr];
    *(u16x8*)(d + (size_t)(c0+dr)*R + r0 + ch) = v;
  }
}

// stage a 64x64 bf16 tile into linear LDS with the read-swizzle pre-applied to
// the source k-chunk (rule 21: filler granule (r, cc^(r&7)) holds A[r][cc*8])
__device__ __forceinline__ void stage_gemm(const u16* __restrict__ src,
                                           int row0, int k0, u16* lds, int tid){
  #pragma unroll
  for (int s2=0; s2<2; ++s2){
    const int slot = tid + s2*256;
    const int row = slot>>3, ch8 = slot&7;
    const int k = k0 + ((ch8 ^ (row&7))<<3);
    gload_lds16(src + (size_t)(row0+row)*DMODEL + k, lds + slot*8);
  }
}

// ---------------- QKV projection -> MFMA-fragment-major K/Q and V^T tiles -------
// Kf[bh][t][frag=ks*4+nj][lane=lg*16+lr][j]  holds K[t*64+nj*16+lr][ks*32+lg*8+j]
// Vf[bh][t][frag=ks*4+dj][lane=lg*16+lr][j]  holds V[t*64+ks*32+lg*8+j][dj*16+lr]
// Epilogue: stage both layouts in LDS, then coalesced 16B stores.
__global__ __launch_bounds__(256) void qkv_gemm(const u16* __restrict__ A,
                                                const u16* __restrict__ W,
                                                u16* __restrict__ Kf,
                                                u16* __restrict__ Vf){
  __shared__ __align__(128) u16 sA[2][4096];
  __shared__ __align__(128) u16 sB[2][4096];
  const int m0 = blockIdx.x*64, n0 = blockIdx.y*64;
  const int tid = threadIdx.x, w = tid>>6, lane = tid&63;
  const int wr = w>>1, wc = w&1;
  const int lr = lane&15, lg = lane>>4;
  f32x4 acc[2][2] = {};
  stage_gemm(A, m0, 0, sA[0], tid);
  stage_gemm(W, n0, 0, sB[0], tid);
  int buf = 0;
  for (int kt=0; kt<8; ++kt){
    __syncthreads();
    if (kt < 7){
      stage_gemm(A, m0, (kt+1)*64, sA[buf^1], tid);
      stage_gemm(W, n0, (kt+1)*64, sB[buf^1], tid);
    }
    #pragma unroll
    for (int ks=0; ks<2; ++ks){
      bf16x8 af[2], bfr[2];
      #pragma unroll
      for (int mi=0; mi<2; ++mi){
        const int r = wr*32 + mi*16 + lr;
        af[mi] = *(const bf16x8*)(&sA[buf][(r*64 + ks*32 + lg*8) ^ ((r&7)<<3)]);
      }
      #pragma unroll
      for (int nj=0; nj<2; ++nj){
        const int r = wc*32 + nj*16 + lr;
        bfr[nj] = *(const bf16x8*)(&sB[buf][(r*64 + ks*32 + lg*8) ^ ((r&7)<<3)]);
      }
      #pragma unroll
      for (int mi=0; mi<2; ++mi)
        #pragma unroll
        for (int nj=0; nj<2; ++nj)
          acc[mi][nj] = MFMA16(af[mi], bfr[nj], acc[mi][nj]);
    }
    buf ^= 1;
  }
  // epilogue: sA[0]/sB[0] free (last iter read sA[1]); no barrier needed before writes
  u16* lK = sA[0];
  u16* lV = sB[0];
  #pragma unroll
  for (int mi=0; mi<2; ++mi)
    #pragma unroll
    for (int nj=0; nj<2; ++nj){
      const int d   = wc*32 + nj*16 + lr;
      const int rr0 = wr*32 + mi*16 + lg*4;
      #pragma unroll
      for (int r=0; r<4; ++r){
        const int rr = rr0 + r;
        lK[((d>>5)*4 + (rr>>4))*512 + (((d>>3)&3)*16 + (rr&15))*8 + (d&7)]
            = f2bf(acc[mi][nj][r]);
      }
      // V layout: k-dim = row; 4 consecutive rows = contiguous fj -> one b64
      u16x4 pv;
      #pragma unroll
      for (int r=0; r<4; ++r) pv[r] = f2bf(acc[mi][nj][r]);
      *(u16x4*)&lV[((rr0>>5)*4 + (d>>4))*512 + (((rr0>>3)&3)*16 + (d&15))*8 + (rr0&7)] = pv;
    }
  __syncthreads();
  const int bb = m0>>10, t = (m0&1023)>>6, hh = n0>>6;
  u16* Kt = Kf + (size_t)(((bb*NHEAD+hh)*16) + t)*4096;
  u16* Vt = Vf + (size_t)(((bb*NHEAD+hh)*16) + t)*4096;
  #pragma unroll
  for (int it=0; it<2; ++it){
    const int off = tid*8 + it*2048;
    *(u16x8*)(Kt + off) = *(const u16x8*)(lK + off);
    *(u16x8*)(Vt + off) = *(const u16x8*)(lV + off);
  }
}

// ---------------- attention: split-K (4 k-tiles/wave), L2-direct, tree merge ----
__global__ __launch_bounds__(256,2) void attn_k(const u16* __restrict__ kf,
                                                const u16* __restrict__ vf,
                                                u16* __restrict__ ao){
  __shared__ __align__(16) u16 sPm[16640];
  const int bid = blockIdx.x;
  const int qt = bid >> 6, bh = bid & 63;     // XCD = bid%8 = bh%8 -> K/V L2-resident
  const int b = bh >> 3, h = bh & 7;
  const u16* Kf = kf + (size_t)bh*16*4096;
  const u16* Vf = vf + (size_t)bh*16*4096;
  const int tid = threadIdx.x, w = tid>>6, lane = tid&63;
  const int lr = lane&15, lg = lane>>4;

  bf16x8 aq[4][2];
  #pragma unroll
  for (int g=0; g<4; ++g)
    #pragma unroll
    for (int ks=0; ks<2; ++ks){
      u16x8 v = *(const u16x8*)(Kf + (size_t)qt*4096 + (ks*4+g)*512 + lane*8);
      bf16x8 t;
      #pragma unroll
      for (int j=0;j<8;j++) t[j] = (short)f2bf(bf2f(v[j])*0.18033688f);
      aq[g][ks] = t;
    }

  f32x4 o[4][4] = {};
  float lsum[4][4] = {};

  for (int t=0; t<4; ++t){
    const int kt = w + t*4;
    const u16* Kt = Kf + (size_t)kt*4096;
    const u16* Vt = Vf + (size_t)kt*4096;
    bf16x8 bk[2][4];
    #pragma unroll
    for (int ks=0; ks<2; ++ks)
      #pragma unroll
      for (int nj=0; nj<4; ++nj)
        bk[ks][nj] = *(const bf16x8*)(Kt + (ks*4+nj)*512 + lane*8);
    #pragma unroll
    for (int g=0; g<4; ++g){
      f32x4 sc[4] = {};
      __builtin_amdgcn_s_setprio(1);
      #pragma unroll
      for (int ks=0; ks<2; ++ks)
        #pragma unroll
        for (int nj=0; nj<4; ++nj)
          sc[nj] = MFMA16(aq[g][ks], bk[ks][nj], sc[nj]);
      __builtin_amdgcn_s_setprio(0);
      const int wp = (w*4+g)*1024;
      #pragma unroll
      for (int nj=0; nj<4; ++nj){
        #pragma unroll
        for (int r=0; r<4; ++r){
          const float p = __builtin_amdgcn_exp2f(sc[nj][r]);
          const unsigned pu = __float_as_uint(p) & 0xFFFF0000u;
          lsum[g][r] += __uint_as_float(pu);
          const int prow = lg*4 + r;
          sPm[wp + ((prow*64 + nj*16 + lr) ^ ((prow&7)<<3))] = (u16)(pu>>16);
        }
      }
    }
    asm volatile("s_waitcnt lgkmcnt(0)" ::: "memory");
    bf16x8 bv[2][4];
    #pragma unroll
    for (int ks=0; ks<2; ++ks)
      #pragma unroll
      for (int dj=0; dj<4; ++dj)
        bv[ks][dj] = *(const bf16x8*)(Vt + (ks*4+dj)*512 + lane*8);
    __builtin_amdgcn_s_setprio(1);
    #pragma unroll
    for (int g=0; g<4; ++g){
      const int wp = (w*4+g)*1024;
      #pragma unroll
      for (int ks=0; ks<2; ++ks){
        bf16x8 pa = *(const bf16x8*)(&sPm[wp + ((lr*64 + ks*32 + lg*8) ^ ((lr&7)<<3))]);
        #pragma unroll
        for (int dj=0; dj<4; ++dj)
          o[g][dj] = MFMA16(pa, bv[ks][dj], o[g][dj]);
      }
    }
    __builtin_amdgcn_s_setprio(0);
  }

  #pragma unroll
  for (int g=0; g<4; ++g)
    #pragma unroll
    for (int r=0; r<4; ++r){
      float s = lsum[g][r];
      s += __shfl_xor(s,1); s += __shfl_xor(s,2);
      s += __shfl_xor(s,4); s += __shfl_xor(s,8);
      lsum[g][r] = s;
    }

  __syncthreads();
  float* mrg = (float*)sPm;
  if (w & 1){
    float* R = mrg + (w>>1)*4160;
    #pragma unroll
    for (int g=0; g<4; ++g){
      #pragma unroll
      for (int dj=0; dj<4; ++dj)
        *(f32x4*)&R[(g*4+dj)*256 + lane*4] = o[g][dj];
      if (lr == 0)
        #pragma unroll
        for (int r=0; r<4; ++r) R[4096 + g*16 + lg*4 + r] = lsum[g][r];
    }
  }
  __syncthreads();
  if (!(w & 1)){
    float* R = mrg + (w>>1)*4160;
    #pragma unroll
    for (int g=0; g<4; ++g){
      #pragma unroll
      for (int dj=0; dj<4; ++dj)
        o[g][dj] += *(const f32x4*)&R[(g*4+dj)*256 + lane*4];
      #pragma unroll
      for (int r=0; r<4; ++r) lsum[g][r] += R[4096 + g*16 + lg*4 + r];
    }
  }
  if (w == 2){
    float* R = mrg + 4160;
    #pragma unroll
    for (int g=0; g<4; ++g){
      #pragma unroll
      for (int dj=0; dj<4; ++dj)
        *(f32x4*)&R[(g*4+dj)*256 + lane*4] = o[g][dj];
      if (lr == 0)
        #pragma unroll
        for (int r=0; r<4; ++r) R[4096 + g*16 + lg*4 + r] = lsum[g][r];
    }
  }
  __syncthreads();
  if (w == 0){
    float* R = mrg + 4160;
    #pragma unroll
    for (int g=0; g<4; ++g){
      #pragma unroll
      for (int dj=0; dj<4; ++dj)
        o[g][dj] += *(const f32x4*)&R[(g*4+dj)*256 + lane*4];
      #pragma unroll
      for (int r=0; r<4; ++r) lsum[g][r] += R[4096 + g*16 + lg*4 + r];
    }
    #pragma unroll
    for (int g=0; g<4; ++g){
      float inv[4];
      #pragma unroll
      for (int r=0; r<4; ++r) inv[r] = __builtin_amdgcn_rcpf(lsum[g][r]);
      const int i0 = qt*64 + g*16;
      #pragma unroll
      for (int dj=0; dj<4; ++dj)
        #pragma unroll
        for (int r=0; r<4; ++r){
          const int l = i0 + lg*4 + r;
          const int d = dj*16 + lr;
          ao[((size_t)(b*LTOK + l))*DMODEL + h*DHEAD + d] = f2bf(o[g][dj][r]*inv[r]);
        }
    }
  }
}

// ---------------- FC projection + bias + residual (coalesced LDS epilogue) ------
__global__ __launch_bounds__(256) void fc_gemm(const u16* __restrict__ A,
                                               const u16* __restrict__ W,
                                               const float* __restrict__ bias,
                                               const u16* __restrict__ resid,
                                               u16* __restrict__ Y){
  __shared__ __align__(128) u16 sA[2][4096];
  __shared__ __align__(128) u16 sB[2][4096];
  const int m0 = blockIdx.x*64, n0 = blockIdx.y*64;
  const int tid = threadIdx.x, w = tid>>6, lane = tid&63;
  const int wr = w>>1, wc = w&1;
  const int lr = lane&15, lg = lane>>4;
  f32x4 acc[2][2] = {};
  stage_gemm(A, m0, 0, sA[0], tid);
  stage_gemm(W, n0, 0, sB[0], tid);
  int buf = 0;
  for (int kt=0; kt<8; ++kt){
    __syncthreads();
    if (kt < 7){
      stage_gemm(A, m0, (kt+1)*64, sA[buf^1], tid);
      stage_gemm(W, n0, (kt+1)*64, sB[buf^1], tid);
    }
    #pragma unroll
    for (int ks=0; ks<2; ++ks){
      bf16x8 af[2], bfr[2];
      #pragma unroll
      for (int mi=0; mi<2; ++mi){
        const int r = wr*32 + mi*16 + lr;
        af[mi] = *(const bf16x8*)(&sA[buf][(r*64 + ks*32 + lg*8) ^ ((r&7)<<3)]);
      }
      #pragma unroll
      for (int nj=0; nj<2; ++nj){
        const int r = wc*32 + nj*16 + lr;
        bfr[nj] = *(const bf16x8*)(&sB[buf][(r*64 + ks*32 + lg*8) ^ ((r&7)<<3)]);
      }
      #pragma unroll
      for (int mi=0; mi<2; ++mi)
        #pragma unroll
        for (int nj=0; nj<2; ++nj)
          acc[mi][nj] = MFMA16(af[mi], bfr[nj], acc[mi][nj]);
    }
    buf ^= 1;
  }
  // epilogue: f32 accumulator through swizzled LDS; coalesced resid/bias/store
  float* lY = (float*)sA;   // 4096 floats = 16KB = all of sA
  #pragma unroll
  for (int mi=0; mi<2; ++mi)
    #pragma unroll
    for (int nj=0; nj<2; ++nj)
      #pragma unroll
      for (int r=0; r<4; ++r){
        const int rr = wr*32 + mi*16 + lg*4 + r;
        const int d  = wc*32 + nj*16 + lr;
        lY[(rr*64 + d) ^ ((rr&7)<<3)] = acc[mi][nj][r];
      }
  __syncthreads();
  #pragma unroll
  for (int it=0; it<2; ++it){
    const int row = (tid>>3) + it*32;
    const int ch  = (tid&7)*8;
    const int idx = (row*64 + ch) ^ ((row&7)<<3);
    f32x4 y0 = *(const f32x4*)&lY[idx];
    f32x4 y1 = *(const f32x4*)&lY[idx+4];
    u16x8 rs = *(const u16x8*)(resid + (size_t)(m0+row)*DMODEL + n0 + ch);
    u16x8 o8;
    #pragma unroll
    for (int j=0;j<4;j++) o8[j]   = f2bf(y0[j] + bias[n0+ch+j]   + bf2f(rs[j]));
    #pragma unroll
    for (int j=0;j<4;j++) o8[j+4] = f2bf(y1[j] + bias[n0+ch+4+j] + bf2f(rs[j+4]));
    *(u16x8*)(Y + (size_t)(m0+row)*DMODEL + n0 + ch) = o8;
  }
}

// ---------------- LayerNorm over 512, one wave per row; fp32 out ----------------
__global__ __launch_bounds__(256) void ln_k(const u16* __restrict__ Y,
                                            const float* __restrict__ gamma,
                                            const float* __restrict__ beta,
                                            float* __restrict__ out){
  const int row = blockIdx.x*4 + (threadIdx.x>>6);
  const int lane = threadIdx.x&63;
  const u16* yr = Y + (size_t)row*DMODEL;
  u16x8 v = *(const u16x8*)(yr + lane*8);
  float x[8]; float s=0.f, sq=0.f;
  #pragma unroll
  for (int j=0;j<8;j++){ x[j]=bf2f(v[j]); s+=x[j]; sq+=x[j]*x[j]; }
  #pragma unroll
  for (int mk=1; mk<64; mk<<=1){ s += __shfl_xor(s,mk); sq += __shfl_xor(sq,mk); }
  const float mean = s*(1.f/DMODEL);
  float var = sq*(1.f/DMODEL) - mean*mean;
  const float rstd = rsqrtf(var + 1e-5f);
  float* po = out + (size_t)row*DMODEL + lane*8;
  #pragma unroll
  for (int j=0;j<8;j++){
    const int c = lane*8+j;
    po[j] = (x[j]-mean)*rstd*gamma[c] + beta[c];
  }
}

extern "C" void kernel_launch(void* const* d_in, const int* in_sizes, int n_in,
                              void* d_out, int out_size, void* d_ws, size_t ws_size,
                              hipStream_t stream){
  (void)in_sizes; (void)n_in; (void)out_size; (void)ws_size;
  const float* q      = (const float*)d_in[0];
  const float* w_qkvs = (const float*)d_in[1];
  const float* fc_w   = (const float*)d_in[2];
  const float* fc_b   = (const float*)d_in[3];
  const float* ln_g   = (const float*)d_in[4];
  const float* ln_b   = (const float*)d_in[5];
  float* out = (float*)d_out;
  char* ws = (char*)d_ws;
  u16* x_rm  = (u16*)(ws);                 // [8192][512] bf16
  u16* kfb   = (u16*)(ws + 8388608);       // fragment-major K/Q tiles
  u16* vfb   = (u16*)(ws + 16777216);      // fragment-major V tiles
  u16* ao    = (u16*)(ws + 25165824);      // [8192][512]
  u16* wqkvb = (u16*)(ws + 33554432);
  u16* wfcb  = (u16*)(ws + 34078720);
  u16* y0    = kfb;                        // reuse after attention

  convert2_k<<<256,256,0,stream>>>(w_qkvs, wqkvb, fc_w, wfcb);
  transpose_f2b<<<dim3(8,16,BATCH),256,0,stream>>>(q, x_rm, DMODEL, LTOK);
  qkv_gemm<<<dim3(128,8),256,0,stream>>>(x_rm, wqkvb, kfb, vfb);
  attn_k<<<1024,256,0,stream>>>(kfb, vfb, ao);
  fc_gemm<<<dim3(128,8),256,0,stream>>>(ao, wfcb, fc_b, x_rm, y0);
  ln_k<<<2048,256,0,stream>>>(y0, ln_g, ln_b, out);
}

// Round 14
// 74.549 us; speedup vs baseline: 1.9498x; 1.0209x over previous
//
#include <hip/hip_runtime.h>
#include <stdint.h>

#define BATCH 8
#define LTOK 1024
#define DMODEL 512
#define NHEAD 8
#define DHEAD 64

typedef unsigned short u16;
typedef u16 u16x4 __attribute__((ext_vector_type(4)));
typedef u16 u16x8 __attribute__((ext_vector_type(8)));
typedef short bf16x8 __attribute__((ext_vector_type(8)));
typedef float f32x4 __attribute__((ext_vector_type(4)));

#define MFMA16(a,b,c) __builtin_amdgcn_mfma_f32_16x16x32_bf16((a),(b),(c),0,0,0)

__device__ __forceinline__ float bf2f(u16 x){
  union{unsigned u; float f;} v; v.u = ((unsigned)x)<<16; return v.f;
}
__device__ __forceinline__ u16 f2bf(float f){
  union{float f; unsigned u;} v; v.f = f;
  unsigned r = v.u + 0x7fffu + ((v.u>>16)&1u);
  return (u16)(r>>16);
}

__device__ __forceinline__ void gload_lds16(const u16* g, u16* l){
  __builtin_amdgcn_global_load_lds(
      (const __attribute__((address_space(1))) void*)g,
      (__attribute__((address_space(3))) void*)l,
      16, 0, 0);
}

// ---------------- fp32 -> bf16 convert, both weight matrices in one launch ------
__global__ __launch_bounds__(256) void convert2_k(const float* __restrict__ s0,
                                                  u16* __restrict__ d0,
                                                  const float* __restrict__ s1,
                                                  u16* __restrict__ d1){
  const int blk = blockIdx.x;
  const float* src = (blk < 128) ? s0 : s1;
  u16* dst        = (blk < 128) ? d0 : d1;
  const int i = (((blk & 127)*256) + threadIdx.x)*8;
  u16x8 v;
  #pragma unroll
  for (int j=0;j<8;j++) v[j] = f2bf(src[i+j]);
  *(u16x8*)(dst + i) = v;
}

// ---------------- 64x64 tiled transpose fp32->bf16: dst[c][r] = src[r][c] -------
__global__ __launch_bounds__(256) void transpose_f2b(const float* __restrict__ src,
                                                     u16* __restrict__ dst,
                                                     int R, int C){
  __shared__ __align__(16) u16 t[64][72];
  const int b  = blockIdx.z;
  const int r0 = blockIdx.x*64, c0 = blockIdx.y*64;
  const float* s = src + (size_t)b*R*C;
  u16* d         = dst + (size_t)b*R*C;
  const int tid = threadIdx.x;
  const int row = tid>>3, ch = (tid&7)*8;
  #pragma unroll
  for (int rr=0; rr<64; rr+=32){
    const float* p = s + (size_t)(r0+row+rr)*C + c0 + ch;
    u16x8 v;
    #pragma unroll
    for (int j=0;j<8;j++) v[j] = f2bf(p[j]);
    *(u16x8*)&t[row+rr][ch] = v;
  }
  __syncthreads();
  #pragma unroll
  for (int rr=0; rr<64; rr+=32){
    const int dr = row+rr;
    u16x8 v;
    #pragma unroll
    for (int j=0;j<8;j++) v[j] = t[ch+j][dr];
    *(u16x8*)(d + (size_t)(c0+dr)*R + r0 + ch) = v;
  }
}

// stage a 128x64 bf16 tile into linear LDS with read-swizzle pre-applied to the
// source k-chunk (rule 21: filler granule (r, cc^(r&7)) holds A[r][cc*8])
__device__ __forceinline__ void stage128(const u16* __restrict__ src,
                                         int row0, int k0, u16* lds, int tid){
  #pragma unroll
  for (int s2=0; s2<4; ++s2){
    const int slot = tid + s2*256;
    const int row = slot>>3, ch8 = slot&7;
    const int k = k0 + ((ch8 ^ (row&7))<<3);
    gload_lds16(src + (size_t)(row0+row)*DMODEL + k, lds + slot*8);
  }
}

// ---------------- QKV projection, 128x128 tile -> frag-major K/Q and V tiles ----
// Kf[bh][t][frag=ks*4+nj][lane=lg*16+lr][j]  holds K[t*64+nj*16+lr][ks*32+lg*8+j]
// Vf[bh][t][frag=ks*4+dj][lane=lg*16+lr][j]  holds V[t*64+ks*32+lg*8+j][dj*16+lr]
__global__ __launch_bounds__(256) void qkv_gemm(const u16* __restrict__ A,
                                                const u16* __restrict__ W,
                                                u16* __restrict__ Kf,
                                                u16* __restrict__ Vf){
  __shared__ __align__(128) u16 smem[32768];   // 64KB arena: A dbuf 32K | B dbuf 32K
  const int m0 = blockIdx.x*128, n0 = blockIdx.y*128;
  const int tid = threadIdx.x, w = tid>>6, lane = tid&63;
  const int wr = w>>1, wc = w&1;
  const int lr = lane&15, lg = lane>>4;
  f32x4 acc[4][4] = {};
  stage128(A, m0, 0, smem, tid);
  stage128(W, n0, 0, smem + 16384, tid);
  int buf = 0;
  for (int kt=0; kt<8; ++kt){
    __syncthreads();
    if (kt < 7){
      stage128(A, m0, (kt+1)*64, smem + (buf^1)*8192, tid);
      stage128(W, n0, (kt+1)*64, smem + 16384 + (buf^1)*8192, tid);
    }
    const u16* sa = smem + buf*8192;
    const u16* sb = smem + 16384 + buf*8192;
    #pragma unroll
    for (int ks=0; ks<2; ++ks){
      bf16x8 af[4], bfr[4];
      #pragma unroll
      for (int mi=0; mi<4; ++mi){
        const int r = wr*64 + mi*16 + lr;
        af[mi] = *(const bf16x8*)(&sa[(r*64 + ks*32 + lg*8) ^ ((r&7)<<3)]);
      }
      #pragma unroll
      for (int nj=0; nj<4; ++nj){
        const int r = wc*64 + nj*16 + lr;
        bfr[nj] = *(const bf16x8*)(&sb[(r*64 + ks*32 + lg*8) ^ ((r&7)<<3)]);
      }
      #pragma unroll
      for (int mi=0; mi<4; ++mi)
        #pragma unroll
        for (int nj=0; nj<4; ++nj)
          acc[mi][nj] = MFMA16(af[mi], bfr[nj], acc[mi][nj]);
    }
    buf ^= 1;
  }
  __syncthreads();                 // final compute read smem[1]/[3]; arena now free
  // wave w owns output tile lt=w: (bh = hh0+wc, t = t0+wr)
  u16* Ktile = smem + w*4096;
  u16* Vtile = smem + 16384 + w*4096;
  #pragma unroll
  for (int mi=0; mi<4; ++mi)
    #pragma unroll
    for (int nj=0; nj<4; ++nj){
      const int rrb = mi*16 + lg*4;          // local l-row base 0..63
      const int d   = nj*16 + lr;            // local d 0..63
      #pragma unroll
      for (int r=0; r<4; ++r){
        const int rr = rrb + r;
        Ktile[((d>>5)*4 + (rr>>4))*512 + (((d>>3)&3)*16 + (rr&15))*8 + (d&7)]
            = f2bf(acc[mi][nj][r]);
      }
      u16x4 pv;
      #pragma unroll
      for (int r=0; r<4; ++r) pv[r] = f2bf(acc[mi][nj][r]);
      *(u16x4*)&Vtile[((rrb>>5)*4 + (d>>4))*512 + (((rrb>>3)&3)*16 + (d&15))*8 + (rrb&7)] = pv;
    }
  __syncthreads();
  const int bb = m0>>10, t0 = (m0&1023)>>6, hh0 = n0>>6;
  #pragma unroll
  for (int p=0; p<8; ++p){
    const int gi = p*2048 + tid*8;
    const int lt = gi>>12, off = gi&4095;
    const size_t base = (size_t)((bb*NHEAD + hh0 + (lt&1))*16 + t0 + (lt>>1))*4096 + off;
    *(u16x8*)(Kf + base) = *(const u16x8*)(smem + gi);
    *(u16x8*)(Vf + base) = *(const u16x8*)(smem + 16384 + gi);
  }
}

// ---------------- attention: split-K (4 k-tiles/wave), L2-direct, tree merge ----
__global__ __launch_bounds__(256,2) void attn_k(const u16* __restrict__ kf,
                                                const u16* __restrict__ vf,
                                                u16* __restrict__ ao){
  __shared__ __align__(16) u16 sPm[16640];
  const int bid = blockIdx.x;
  const int qt = bid >> 6, bh = bid & 63;     // XCD = bid%8 = bh%8 -> K/V L2-resident
  const int b = bh >> 3, h = bh & 7;
  const u16* Kf = kf + (size_t)bh*16*4096;
  const u16* Vf = vf + (size_t)bh*16*4096;
  const int tid = threadIdx.x, w = tid>>6, lane = tid&63;
  const int lr = lane&15, lg = lane>>4;

  bf16x8 aq[4][2];
  #pragma unroll
  for (int g=0; g<4; ++g)
    #pragma unroll
    for (int ks=0; ks<2; ++ks){
      u16x8 v = *(const u16x8*)(Kf + (size_t)qt*4096 + (ks*4+g)*512 + lane*8);
      bf16x8 t;
      #pragma unroll
      for (int j=0;j<8;j++) t[j] = (short)f2bf(bf2f(v[j])*0.18033688f);
      aq[g][ks] = t;
    }

  f32x4 o[4][4] = {};
  float lsum[4][4] = {};

  for (int t=0; t<4; ++t){
    const int kt = w + t*4;
    const u16* Kt = Kf + (size_t)kt*4096;
    const u16* Vt = Vf + (size_t)kt*4096;
    bf16x8 bk[2][4];
    #pragma unroll
    for (int ks=0; ks<2; ++ks)
      #pragma unroll
      for (int nj=0; nj<4; ++nj)
        bk[ks][nj] = *(const bf16x8*)(Kt + (ks*4+nj)*512 + lane*8);
    #pragma unroll
    for (int g=0; g<4; ++g){
      f32x4 sc[4] = {};
      __builtin_amdgcn_s_setprio(1);
      #pragma unroll
      for (int ks=0; ks<2; ++ks)
        #pragma unroll
        for (int nj=0; nj<4; ++nj)
          sc[nj] = MFMA16(aq[g][ks], bk[ks][nj], sc[nj]);
      __builtin_amdgcn_s_setprio(0);
      const int wp = (w*4+g)*1024;
      #pragma unroll
      for (int nj=0; nj<4; ++nj){
        #pragma unroll
        for (int r=0; r<4; ++r){
          const float p = __builtin_amdgcn_exp2f(sc[nj][r]);
          const unsigned pu = __float_as_uint(p) & 0xFFFF0000u;
          lsum[g][r] += __uint_as_float(pu);
          const int prow = lg*4 + r;
          sPm[wp + ((prow*64 + nj*16 + lr) ^ ((prow&7)<<3))] = (u16)(pu>>16);
        }
      }
    }
    asm volatile("s_waitcnt lgkmcnt(0)" ::: "memory");
    bf16x8 bv[2][4];
    #pragma unroll
    for (int ks=0; ks<2; ++ks)
      #pragma unroll
      for (int dj=0; dj<4; ++dj)
        bv[ks][dj] = *(const bf16x8*)(Vt + (ks*4+dj)*512 + lane*8);
    __builtin_amdgcn_s_setprio(1);
    #pragma unroll
    for (int g=0; g<4; ++g){
      const int wp = (w*4+g)*1024;
      #pragma unroll
      for (int ks=0; ks<2; ++ks){
        bf16x8 pa = *(const bf16x8*)(&sPm[wp + ((lr*64 + ks*32 + lg*8) ^ ((lr&7)<<3))]);
        #pragma unroll
        for (int dj=0; dj<4; ++dj)
          o[g][dj] = MFMA16(pa, bv[ks][dj], o[g][dj]);
      }
    }
    __builtin_amdgcn_s_setprio(0);
  }

  #pragma unroll
  for (int g=0; g<4; ++g)
    #pragma unroll
    for (int r=0; r<4; ++r){
      float s = lsum[g][r];
      s += __shfl_xor(s,1); s += __shfl_xor(s,2);
      s += __shfl_xor(s,4); s += __shfl_xor(s,8);
      lsum[g][r] = s;
    }

  __syncthreads();
  float* mrg = (float*)sPm;
  if (w & 1){
    float* R = mrg + (w>>1)*4160;
    #pragma unroll
    for (int g=0; g<4; ++g){
      #pragma unroll
      for (int dj=0; dj<4; ++dj)
        *(f32x4*)&R[(g*4+dj)*256 + lane*4] = o[g][dj];
      if (lr == 0)
        #pragma unroll
        for (int r=0; r<4; ++r) R[4096 + g*16 + lg*4 + r] = lsum[g][r];
    }
  }
  __syncthreads();
  if (!(w & 1)){
    float* R = mrg + (w>>1)*4160;
    #pragma unroll
    for (int g=0; g<4; ++g){
      #pragma unroll
      for (int dj=0; dj<4; ++dj)
        o[g][dj] += *(const f32x4*)&R[(g*4+dj)*256 + lane*4];
      #pragma unroll
      for (int r=0; r<4; ++r) lsum[g][r] += R[4096 + g*16 + lg*4 + r];
    }
  }
  if (w == 2){
    float* R = mrg + 4160;
    #pragma unroll
    for (int g=0; g<4; ++g){
      #pragma unroll
      for (int dj=0; dj<4; ++dj)
        *(f32x4*)&R[(g*4+dj)*256 + lane*4] = o[g][dj];
      if (lr == 0)
        #pragma unroll
        for (int r=0; r<4; ++r) R[4096 + g*16 + lg*4 + r] = lsum[g][r];
    }
  }
  __syncthreads();
  if (w == 0){
    float* R = mrg + 4160;
    #pragma unroll
    for (int g=0; g<4; ++g){
      #pragma unroll
      for (int dj=0; dj<4; ++dj)
        o[g][dj] += *(const f32x4*)&R[(g*4+dj)*256 + lane*4];
      #pragma unroll
      for (int r=0; r<4; ++r) lsum[g][r] += R[4096 + g*16 + lg*4 + r];
    }
    #pragma unroll
    for (int g=0; g<4; ++g){
      float inv[4];
      #pragma unroll
      for (int r=0; r<4; ++r) inv[r] = __builtin_amdgcn_rcpf(lsum[g][r]);
      const int i0 = qt*64 + g*16;
      #pragma unroll
      for (int dj=0; dj<4; ++dj)
        #pragma unroll
        for (int r=0; r<4; ++r){
          const int l = i0 + lg*4 + r;
          const int d = dj*16 + lr;
          ao[((size_t)(b*LTOK + l))*DMODEL + h*DHEAD + d] = f2bf(o[g][dj][r]*inv[r]);
        }
    }
  }
}

// ---------------- FC projection, 128x128 tile + bias + residual -----------------
__global__ __launch_bounds__(256) void fc_gemm(const u16* __restrict__ A,
                                               const u16* __restrict__ W,
                                               const float* __restrict__ bias,
                                               const u16* __restrict__ resid,
                                               u16* __restrict__ Y){
  __shared__ __align__(128) u16 smem[32768];
  const int m0 = blockIdx.x*128, n0 = blockIdx.y*128;
  const int tid = threadIdx.x, w = tid>>6, lane = tid&63;
  const int wr = w>>1, wc = w&1;
  const int lr = lane&15, lg = lane>>4;
  f32x4 acc[4][4] = {};
  stage128(A, m0, 0, smem, tid);
  stage128(W, n0, 0, smem + 16384, tid);
  int buf = 0;
  for (int kt=0; kt<8; ++kt){
    __syncthreads();
    if (kt < 7){
      stage128(A, m0, (kt+1)*64, smem + (buf^1)*8192, tid);
      stage128(W, n0, (kt+1)*64, smem + 16384 + (buf^1)*8192, tid);
    }
    const u16* sa = smem + buf*8192;
    const u16* sb = smem + 16384 + buf*8192;
    #pragma unroll
    for (int ks=0; ks<2; ++ks){
      bf16x8 af[4], bfr[4];
      #pragma unroll
      for (int mi=0; mi<4; ++mi){
        const int r = wr*64 + mi*16 + lr;
        af[mi] = *(const bf16x8*)(&sa[(r*64 + ks*32 + lg*8) ^ ((r&7)<<3)]);
      }
      #pragma unroll
      for (int nj=0; nj<4; ++nj){
        const int r = wc*64 + nj*16 + lr;
        bfr[nj] = *(const bf16x8*)(&sb[(r*64 + ks*32 + lg*8) ^ ((r&7)<<3)]);
      }
      #pragma unroll
      for (int mi=0; mi<4; ++mi)
        #pragma unroll
        for (int nj=0; nj<4; ++nj)
          acc[mi][nj] = MFMA16(af[mi], bfr[nj], acc[mi][nj]);
    }
    buf ^= 1;
  }
  __syncthreads();                 // arena free; stage f32 results (64KB exactly)
  float* lY = (float*)smem;
  #pragma unroll
  for (int mi=0; mi<4; ++mi)
    #pragma unroll
    for (int nj=0; nj<4; ++nj)
      #pragma unroll
      for (int r=0; r<4; ++r){
        const int rr = wr*64 + mi*16 + lg*4 + r;
        const int d  = wc*64 + nj*16 + lr;
        lY[rr*128 + (d ^ ((rr&7)<<2))] = acc[mi][nj][r];
      }
  __syncthreads();
  #pragma unroll
  for (int p=0; p<8; ++p){
    const int slot = p*256 + tid;
    const int row = slot>>4;
    const int ch  = (slot&15)*8;
    const int x   = (row&7)<<2;
    f32x4 ya = *(const f32x4*)&lY[row*128 + (ch ^ x)];
    f32x4 yb = *(const f32x4*)&lY[row*128 + ((ch+4) ^ x)];
    u16x8 rs = *(const u16x8*)(resid + (size_t)(m0+row)*DMODEL + n0 + ch);
    u16x8 o8;
    #pragma unroll
    for (int j=0;j<4;j++) o8[j]   = f2bf(ya[j] + bias[n0+ch+j]   + bf2f(rs[j]));
    #pragma unroll
    for (int j=0;j<4;j++) o8[j+4] = f2bf(yb[j] + bias[n0+ch+4+j] + bf2f(rs[j+4]));
    *(u16x8*)(Y + (size_t)(m0+row)*DMODEL + n0 + ch) = o8;
  }
}

// ---------------- LayerNorm over 512, one wave per row; fp32 out ----------------
__global__ __launch_bounds__(256) void ln_k(const u16* __restrict__ Y,
                                            const float* __restrict__ gamma,
                                            const float* __restrict__ beta,
                                            float* __restrict__ out){
  const int row = blockIdx.x*4 + (threadIdx.x>>6);
  const int lane = threadIdx.x&63;
  const u16* yr = Y + (size_t)row*DMODEL;
  u16x8 v = *(const u16x8*)(yr + lane*8);
  float x[8]; float s=0.f, sq=0.f;
  #pragma unroll
  for (int j=0;j<8;j++){ x[j]=bf2f(v[j]); s+=x[j]; sq+=x[j]*x[j]; }
  #pragma unroll
  for (int mk=1; mk<64; mk<<=1){ s += __shfl_xor(s,mk); sq += __shfl_xor(sq,mk); }
  const float mean = s*(1.f/DMODEL);
  float var = sq*(1.f/DMODEL) - mean*mean;
  const float rstd = rsqrtf(var + 1e-5f);
  float* po = out + (size_t)row*DMODEL + lane*8;
  #pragma unroll
  for (int j=0;j<8;j++){
    const int c = lane*8+j;
    po[j] = (x[j]-mean)*rstd*gamma[c] + beta[c];
  }
}

extern "C" void kernel_launch(void* const* d_in, const int* in_sizes, int n_in,
                              void* d_out, int out_size, void* d_ws, size_t ws_size,
                              hipStream_t stream){
  (void)in_sizes; (void)n_in; (void)out_size; (void)ws_size;
  const float* q      = (const float*)d_in[0];
  const float* w_qkvs = (const float*)d_in[1];
  const float* fc_w   = (const float*)d_in[2];
  const float* fc_b   = (const float*)d_in[3];
  const float* ln_g   = (const float*)d_in[4];
  const float* ln_b   = (const float*)d_in[5];
  float* out = (float*)d_out;
  char* ws = (char*)d_ws;
  u16* x_rm  = (u16*)(ws);                 // [8192][512] bf16
  u16* kfb   = (u16*)(ws + 8388608);       // fragment-major K/Q tiles
  u16* vfb   = (u16*)(ws + 16777216);      // fragment-major V tiles
  u16* ao    = (u16*)(ws + 25165824);      // [8192][512]
  u16* wqkvb = (u16*)(ws + 33554432);
  u16* wfcb  = (u16*)(ws + 34078720);
  u16* y0    = kfb;                        // reuse after attention

  convert2_k<<<256,256,0,stream>>>(w_qkvs, wqkvb, fc_w, wfcb);
  transpose_f2b<<<dim3(8,16,BATCH),256,0,stream>>>(q, x_rm, DMODEL, LTOK);
  qkv_gemm<<<dim3(64,4),256,0,stream>>>(x_rm, wqkvb, kfb, vfb);
  attn_k<<<1024,256,0,stream>>>(kfb, vfb, ao);
  fc_gemm<<<dim3(64,4),256,0,stream>>>(ao, wfcb, fc_b, x_rm, y0);
  ln_k<<<2048,256,0,stream>>>(y0, ln_g, ln_b, out);
}

// Round 15
// 68.853 us; speedup vs baseline: 2.1111x; 1.0827x over previous
//
#include <hip/hip_runtime.h>
#include <stdint.h>

#define BATCH 8
#define LTOK 1024
#define DMODEL 512
#define NHEAD 8
#define DHEAD 64

typedef unsigned short u16;
typedef u16 u16x4 __attribute__((ext_vector_type(4)));
typedef u16 u16x8 __attribute__((ext_vector_type(8)));
typedef short bf16x8 __attribute__((ext_vector_type(8)));
typedef float f32x4 __attribute__((ext_vector_type(4)));

#define MFMA16(a,b,c) __builtin_amdgcn_mfma_f32_16x16x32_bf16((a),(b),(c),0,0,0)

__device__ __forceinline__ float bf2f(u16 x){
  union{unsigned u; float f;} v; v.u = ((unsigned)x)<<16; return v.f;
}
__device__ __forceinline__ u16 f2bf(float f){
  union{float f; unsigned u;} v; v.f = f;
  unsigned r = v.u + 0x7fffu + ((v.u>>16)&1u);
  return (u16)(r>>16);
}

__device__ __forceinline__ void gload_lds16(const u16* g, u16* l){
  __builtin_amdgcn_global_load_lds(
      (const __attribute__((address_space(1))) void*)g,
      (__attribute__((address_space(3))) void*)l,
      16, 0, 0);
}

// ---------------- prep: transpose q (blocks 0..1023) + convert weights (1024..1279)
__global__ __launch_bounds__(256) void prep_k(const float* __restrict__ q,
                                              u16* __restrict__ x_rm,
                                              const float* __restrict__ w0,
                                              u16* __restrict__ d0,
                                              const float* __restrict__ w1,
                                              u16* __restrict__ d1){
  __shared__ __align__(16) u16 t[64][72];
  const int blk = blockIdx.x;
  const int tid = threadIdx.x;
  if (blk < 1024){
    // 64x64 tiled transpose fp32->bf16: x_rm[b][l][c] = q[b][c][l]
    const int bx = blk & 7, by = (blk>>3) & 15, bz = blk>>7;
    const int r0 = bx*64, c0 = by*64;
    const float* s = q    + (size_t)bz*DMODEL*LTOK;
    u16* d         = x_rm + (size_t)bz*DMODEL*LTOK;
    const int row = tid>>3, ch = (tid&7)*8;
    #pragma unroll
    for (int rr=0; rr<64; rr+=32){
      const float* p = s + (size_t)(r0+row+rr)*LTOK + c0 + ch;
      u16x8 v;
      #pragma unroll
      for (int j=0;j<8;j++) v[j] = f2bf(p[j]);
      *(u16x8*)&t[row+rr][ch] = v;
    }
    __syncthreads();
    #pragma unroll
    for (int rr=0; rr<64; rr+=32){
      const int dr = row+rr;
      u16x8 v;
      #pragma unroll
      for (int j=0;j<8;j++) v[j] = t[ch+j][dr];
      *(u16x8*)(d + (size_t)(c0+dr)*DMODEL + r0 + ch) = v;
    }
  } else {
    const int b2 = blk - 1024;
    const float* src = (b2 < 128) ? w0 : w1;
    u16* dst        = (b2 < 128) ? d0 : d1;
    const int i = (((b2 & 127)*256) + tid)*8;
    u16x8 v;
    #pragma unroll
    for (int j=0;j<8;j++) v[j] = f2bf(src[i+j]);
    *(u16x8*)(dst + i) = v;
  }
}

// stage a 128x64 bf16 tile into linear LDS with read-swizzle pre-applied to the
// source k-chunk (rule 21: filler granule (r, cc^(r&7)) holds A[r][cc*8])
__device__ __forceinline__ void stage128(const u16* __restrict__ src,
                                         int row0, int k0, u16* lds, int tid){
  #pragma unroll
  for (int s2=0; s2<4; ++s2){
    const int slot = tid + s2*256;
    const int row = slot>>3, ch8 = slot&7;
    const int k = k0 + ((ch8 ^ (row&7))<<3);
    gload_lds16(src + (size_t)(row0+row)*DMODEL + k, lds + slot*8);
  }
}

// ---------------- QKV projection, 128x128 tile -> frag-major K/Q and V tiles ----
// Kf[bh][t][frag=ks*4+nj][lane=lg*16+lr][j]  holds K[t*64+nj*16+lr][ks*32+lg*8+j]
// Vf[bh][t][frag=ks*4+dj][lane=lg*16+lr][j]  holds V[t*64+ks*32+lg*8+j][dj*16+lr]
__global__ __launch_bounds__(256) void qkv_gemm(const u16* __restrict__ A,
                                                const u16* __restrict__ W,
                                                u16* __restrict__ Kf,
                                                u16* __restrict__ Vf){
  __shared__ __align__(128) u16 smem[32768];   // 64KB arena: A dbuf 32K | B dbuf 32K
  const int m0 = blockIdx.x*128, n0 = blockIdx.y*128;
  const int tid = threadIdx.x, w = tid>>6, lane = tid&63;
  const int wr = w>>1, wc = w&1;
  const int lr = lane&15, lg = lane>>4;
  f32x4 acc[4][4] = {};
  stage128(A, m0, 0, smem, tid);
  stage128(W, n0, 0, smem + 16384, tid);
  int buf = 0;
  for (int kt=0; kt<8; ++kt){
    __syncthreads();
    if (kt < 7){
      stage128(A, m0, (kt+1)*64, smem + (buf^1)*8192, tid);
      stage128(W, n0, (kt+1)*64, smem + 16384 + (buf^1)*8192, tid);
    }
    const u16* sa = smem + buf*8192;
    const u16* sb = smem + 16384 + buf*8192;
    #pragma unroll
    for (int ks=0; ks<2; ++ks){
      bf16x8 af[4], bfr[4];
      #pragma unroll
      for (int mi=0; mi<4; ++mi){
        const int r = wr*64 + mi*16 + lr;
        af[mi] = *(const bf16x8*)(&sa[(r*64 + ks*32 + lg*8) ^ ((r&7)<<3)]);
      }
      #pragma unroll
      for (int nj=0; nj<4; ++nj){
        const int r = wc*64 + nj*16 + lr;
        bfr[nj] = *(const bf16x8*)(&sb[(r*64 + ks*32 + lg*8) ^ ((r&7)<<3)]);
      }
      #pragma unroll
      for (int mi=0; mi<4; ++mi)
        #pragma unroll
        for (int nj=0; nj<4; ++nj)
          acc[mi][nj] = MFMA16(af[mi], bfr[nj], acc[mi][nj]);
    }
    buf ^= 1;
  }
  __syncthreads();                 // final compute read smem[1]/[3]; arena now free
  u16* Ktile = smem + w*4096;
  u16* Vtile = smem + 16384 + w*4096;
  #pragma unroll
  for (int mi=0; mi<4; ++mi)
    #pragma unroll
    for (int nj=0; nj<4; ++nj){
      const int rrb = mi*16 + lg*4;
      const int d   = nj*16 + lr;
      #pragma unroll
      for (int r=0; r<4; ++r){
        const int rr = rrb + r;
        Ktile[((d>>5)*4 + (rr>>4))*512 + (((d>>3)&3)*16 + (rr&15))*8 + (d&7)]
            = f2bf(acc[mi][nj][r]);
      }
      u16x4 pv;
      #pragma unroll
      for (int r=0; r<4; ++r) pv[r] = f2bf(acc[mi][nj][r]);
      *(u16x4*)&Vtile[((rrb>>5)*4 + (d>>4))*512 + (((rrb>>3)&3)*16 + (d&15))*8 + (rrb&7)] = pv;
    }
  __syncthreads();
  const int bb = m0>>10, t0 = (m0&1023)>>6, hh0 = n0>>6;
  #pragma unroll
  for (int p=0; p<8; ++p){
    const int gi = p*2048 + tid*8;
    const int lt = gi>>12, off = gi&4095;
    const size_t base = (size_t)((bb*NHEAD + hh0 + (lt&1))*16 + t0 + (lt>>1))*4096 + off;
    *(u16x8*)(Kf + base) = *(const u16x8*)(smem + gi);
    *(u16x8*)(Vf + base) = *(const u16x8*)(smem + 16384 + gi);
  }
}

// ---------------- attention: split-K (4 k-tiles/wave), L2-direct, tree merge ----
__global__ __launch_bounds__(256,2) void attn_k(const u16* __restrict__ kf,
                                                const u16* __restrict__ vf,
                                                u16* __restrict__ ao){
  __shared__ __align__(16) u16 sPm[16640];
  const int bid = blockIdx.x;
  const int qt = bid >> 6, bh = bid & 63;     // XCD = bid%8 = bh%8 -> K/V L2-resident
  const int b = bh >> 3, h = bh & 7;
  const u16* Kf = kf + (size_t)bh*16*4096;
  const u16* Vf = vf + (size_t)bh*16*4096;
  const int tid = threadIdx.x, w = tid>>6, lane = tid&63;
  const int lr = lane&15, lg = lane>>4;

  bf16x8 aq[4][2];
  #pragma unroll
  for (int g=0; g<4; ++g)
    #pragma unroll
    for (int ks=0; ks<2; ++ks){
      u16x8 v = *(const u16x8*)(Kf + (size_t)qt*4096 + (ks*4+g)*512 + lane*8);
      bf16x8 t;
      #pragma unroll
      for (int j=0;j<8;j++) t[j] = (short)f2bf(bf2f(v[j])*0.18033688f);
      aq[g][ks] = t;
    }

  f32x4 o[4][4] = {};
  float lsum[4][4] = {};

  for (int t=0; t<4; ++t){
    const int kt = w + t*4;
    const u16* Kt = Kf + (size_t)kt*4096;
    const u16* Vt = Vf + (size_t)kt*4096;
    bf16x8 bk[2][4];
    #pragma unroll
    for (int ks=0; ks<2; ++ks)
      #pragma unroll
      for (int nj=0; nj<4; ++nj)
        bk[ks][nj] = *(const bf16x8*)(Kt + (ks*4+nj)*512 + lane*8);
    #pragma unroll
    for (int g=0; g<4; ++g){
      f32x4 sc[4] = {};
      __builtin_amdgcn_s_setprio(1);
      #pragma unroll
      for (int ks=0; ks<2; ++ks)
        #pragma unroll
        for (int nj=0; nj<4; ++nj)
          sc[nj] = MFMA16(aq[g][ks], bk[ks][nj], sc[nj]);
      __builtin_amdgcn_s_setprio(0);
      const int wp = (w*4+g)*1024;
      #pragma unroll
      for (int nj=0; nj<4; ++nj){
        #pragma unroll
        for (int r=0; r<4; ++r){
          const float p = __builtin_amdgcn_exp2f(sc[nj][r]);
          lsum[g][r] += p;
          const int prow = lg*4 + r;
          sPm[wp + ((prow*64 + nj*16 + lr) ^ ((prow&7)<<3))]
              = (u16)(__float_as_uint(p)>>16);
        }
      }
    }
    asm volatile("s_waitcnt lgkmcnt(0)" ::: "memory");
    bf16x8 bv[2][4];
    #pragma unroll
    for (int ks=0; ks<2; ++ks)
      #pragma unroll
      for (int dj=0; dj<4; ++dj)
        bv[ks][dj] = *(const bf16x8*)(Vt + (ks*4+dj)*512 + lane*8);
    __builtin_amdgcn_s_setprio(1);
    #pragma unroll
    for (int g=0; g<4; ++g){
      const int wp = (w*4+g)*1024;
      #pragma unroll
      for (int ks=0; ks<2; ++ks){
        bf16x8 pa = *(const bf16x8*)(&sPm[wp + ((lr*64 + ks*32 + lg*8) ^ ((lr&7)<<3))]);
        #pragma unroll
        for (int dj=0; dj<4; ++dj)
          o[g][dj] = MFMA16(pa, bv[ks][dj], o[g][dj]);
      }
    }
    __builtin_amdgcn_s_setprio(0);
  }

  #pragma unroll
  for (int g=0; g<4; ++g)
    #pragma unroll
    for (int r=0; r<4; ++r){
      float s = lsum[g][r];
      s += __shfl_xor(s,1); s += __shfl_xor(s,2);
      s += __shfl_xor(s,4); s += __shfl_xor(s,8);
      lsum[g][r] = s;
    }

  __syncthreads();
  float* mrg = (float*)sPm;
  if (w & 1){
    float* R = mrg + (w>>1)*4160;
    #pragma unroll
    for (int g=0; g<4; ++g){
      #pragma unroll
      for (int dj=0; dj<4; ++dj)
        *(f32x4*)&R[(g*4+dj)*256 + lane*4] = o[g][dj];
      if (lr == 0)
        #pragma unroll
        for (int r=0; r<4; ++r) R[4096 + g*16 + lg*4 + r] = lsum[g][r];
    }
  }
  __syncthreads();
  if (!(w & 1)){
    float* R = mrg + (w>>1)*4160;
    #pragma unroll
    for (int g=0; g<4; ++g){
      #pragma unroll
      for (int dj=0; dj<4; ++dj)
        o[g][dj] += *(const f32x4*)&R[(g*4+dj)*256 + lane*4];
      #pragma unroll
      for (int r=0; r<4; ++r) lsum[g][r] += R[4096 + g*16 + lg*4 + r];
    }
  }
  if (w == 2){
    float* R = mrg + 4160;
    #pragma unroll
    for (int g=0; g<4; ++g){
      #pragma unroll
      for (int dj=0; dj<4; ++dj)
        *(f32x4*)&R[(g*4+dj)*256 + lane*4] = o[g][dj];
      if (lr == 0)
        #pragma unroll
        for (int r=0; r<4; ++r) R[4096 + g*16 + lg*4 + r] = lsum[g][r];
    }
  }
  __syncthreads();
  if (w == 0){
    float* R = mrg + 4160;
    #pragma unroll
    for (int g=0; g<4; ++g){
      #pragma unroll
      for (int dj=0; dj<4; ++dj)
        o[g][dj] += *(const f32x4*)&R[(g*4+dj)*256 + lane*4];
      #pragma unroll
      for (int r=0; r<4; ++r) lsum[g][r] += R[4096 + g*16 + lg*4 + r];
    }
    #pragma unroll
    for (int g=0; g<4; ++g){
      float inv[4];
      #pragma unroll
      for (int r=0; r<4; ++r) inv[r] = __builtin_amdgcn_rcpf(lsum[g][r]);
      const int i0 = qt*64 + g*16;
      #pragma unroll
      for (int dj=0; dj<4; ++dj)
        #pragma unroll
        for (int r=0; r<4; ++r){
          const int l = i0 + lg*4 + r;
          const int d = dj*16 + lr;
          ao[((size_t)(b*LTOK + l))*DMODEL + h*DHEAD + d] = f2bf(o[g][dj][r]*inv[r]);
        }
    }
  }
}

// ---------------- FC projection, 128x128 tile + bias + residual -----------------
__global__ __launch_bounds__(256) void fc_gemm(const u16* __restrict__ A,
                                               const u16* __restrict__ W,
                                               const float* __restrict__ bias,
                                               const u16* __restrict__ resid,
                                               u16* __restrict__ Y){
  __shared__ __align__(128) u16 smem[32768];
  const int m0 = blockIdx.x*128, n0 = blockIdx.y*128;
  const int tid = threadIdx.x, w = tid>>6, lane = tid&63;
  const int wr = w>>1, wc = w&1;
  const int lr = lane&15, lg = lane>>4;
  f32x4 acc[4][4] = {};
  stage128(A, m0, 0, smem, tid);
  stage128(W, n0, 0, smem + 16384, tid);
  int buf = 0;
  for (int kt=0; kt<8; ++kt){
    __syncthreads();
    if (kt < 7){
      stage128(A, m0, (kt+1)*64, smem + (buf^1)*8192, tid);
      stage128(W, n0, (kt+1)*64, smem + 16384 + (buf^1)*8192, tid);
    }
    const u16* sa = smem + buf*8192;
    const u16* sb = smem + 16384 + buf*8192;
    #pragma unroll
    for (int ks=0; ks<2; ++ks){
      bf16x8 af[4], bfr[4];
      #pragma unroll
      for (int mi=0; mi<4; ++mi){
        const int r = wr*64 + mi*16 + lr;
        af[mi] = *(const bf16x8*)(&sa[(r*64 + ks*32 + lg*8) ^ ((r&7)<<3)]);
      }
      #pragma unroll
      for (int nj=0; nj<4; ++nj){
        const int r = wc*64 + nj*16 + lr;
        bfr[nj] = *(const bf16x8*)(&sb[(r*64 + ks*32 + lg*8) ^ ((r&7)<<3)]);
      }
      #pragma unroll
      for (int mi=0; mi<4; ++mi)
        #pragma unroll
        for (int nj=0; nj<4; ++nj)
          acc[mi][nj] = MFMA16(af[mi], bfr[nj], acc[mi][nj]);
    }
    buf ^= 1;
  }
  __syncthreads();                 // arena free; stage f32 results (64KB exactly)
  float* lY = (float*)smem;
  #pragma unroll
  for (int mi=0; mi<4; ++mi)
    #pragma unroll
    for (int nj=0; nj<4; ++nj)
      #pragma unroll
      for (int r=0; r<4; ++r){
        const int rr = wr*64 + mi*16 + lg*4 + r;
        const int d  = wc*64 + nj*16 + lr;
        lY[rr*128 + (d ^ ((rr&7)<<2))] = acc[mi][nj][r];
      }
  __syncthreads();
  #pragma unroll
  for (int p=0; p<8; ++p){
    const int slot = p*256 + tid;
    const int row = slot>>4;
    const int ch  = (slot&15)*8;
    const int x   = (row&7)<<2;
    f32x4 ya = *(const f32x4*)&lY[row*128 + (ch ^ x)];
    f32x4 yb = *(const f32x4*)&lY[row*128 + ((ch+4) ^ x)];
    u16x8 rs = *(const u16x8*)(resid + (size_t)(m0+row)*DMODEL + n0 + ch);
    u16x8 o8;
    #pragma unroll
    for (int j=0;j<4;j++) o8[j]   = f2bf(ya[j] + bias[n0+ch+j]   + bf2f(rs[j]));
    #pragma unroll
    for (int j=0;j<4;j++) o8[j+4] = f2bf(yb[j] + bias[n0+ch+4+j] + bf2f(rs[j+4]));
    *(u16x8*)(Y + (size_t)(m0+row)*DMODEL + n0 + ch) = o8;
  }
}

// ---------------- LayerNorm over 512, one wave per row; fp32 out ----------------
__global__ __launch_bounds__(256) void ln_k(const u16* __restrict__ Y,
                                            const float* __restrict__ gamma,
                                            const float* __restrict__ beta,
                                            float* __restrict__ out){
  const int row = blockIdx.x*4 + (threadIdx.x>>6);
  const int lane = threadIdx.x&63;
  const u16* yr = Y + (size_t)row*DMODEL;
  u16x8 v = *(const u16x8*)(yr + lane*8);
  float x[8]; float s=0.f, sq=0.f;
  #pragma unroll
  for (int j=0;j<8;j++){ x[j]=bf2f(v[j]); s+=x[j]; sq+=x[j]*x[j]; }
  #pragma unroll
  for (int mk=1; mk<64; mk<<=1){ s += __shfl_xor(s,mk); sq += __shfl_xor(sq,mk); }
  const float mean = s*(1.f/DMODEL);
  float var = sq*(1.f/DMODEL) - mean*mean;
  const float rstd = rsqrtf(var + 1e-5f);
  float* po = out + (size_t)row*DMODEL + lane*8;
  #pragma unroll
  for (int j=0;j<8;j++){
    const int c = lane*8+j;
    po[j] = (x[j]-mean)*rstd*gamma[c] + beta[c];
  }
}

extern "C" void kernel_launch(void* const* d_in, const int* in_sizes, int n_in,
                              void* d_out, int out_size, void* d_ws, size_t ws_size,
                              hipStream_t stream){
  (void)in_sizes; (void)n_in; (void)out_size; (void)ws_size;
  const float* q      = (const float*)d_in[0];
  const float* w_qkvs = (const float*)d_in[1];
  const float* fc_w   = (const float*)d_in[2];
  const float* fc_b   = (const float*)d_in[3];
  const float* ln_g   = (const float*)d_in[4];
  const float* ln_b   = (const float*)d_in[5];
  float* out = (float*)d_out;
  char* ws = (char*)d_ws;
  u16* x_rm  = (u16*)(ws);                 // [8192][512] bf16
  u16* kfb   = (u16*)(ws + 8388608);       // fragment-major K/Q tiles
  u16* vfb   = (u16*)(ws + 16777216);      // fragment-major V tiles
  u16* ao    = (u16*)(ws + 25165824);      // [8192][512]
  u16* wqkvb = (u16*)(ws + 33554432);
  u16* wfcb  = (u16*)(ws + 34078720);
  u16* y0    = kfb;                        // reuse after attention

  prep_k<<<1280,256,0,stream>>>(q, x_rm, w_qkvs, wqkvb, fc_w, wfcb);
  qkv_gemm<<<dim3(64,4),256,0,stream>>>(x_rm, wqkvb, kfb, vfb);
  attn_k<<<1024,256,0,stream>>>(kfb, vfb, ao);
  fc_gemm<<<dim3(64,4),256,0,stream>>>(ao, wfcb, fc_b, x_rm, y0);
  ln_k<<<2048,256,0,stream>>>(y0, ln_g, ln_b, out);
}